// Round 6
// baseline (1510.878 us; speedup 1.0000x reference)
//
#include <hip/hip_runtime.h>
#include <cstdint>
#include <cstddef>

#define SS 512
#define BB 64
#define DD 128
#define HH 8
#define HDIM 16
#define FFD 1024
#define NL 6

typedef short bf16x8 __attribute__((ext_vector_type(8)));
typedef float f32x4 __attribute__((ext_vector_type(4)));

// hardware packed f32->bf16 (RNE), low16 = a, high16 = b
__device__ inline uint32_t pack2(float a, float b) {
  uint32_t r;
  asm("v_cvt_pk_bf16_f32 %0, %1, %2" : "=v"(r) : "v"(a), "v"(b));
  return r;
}

#define QSCALE 0.36067376022224085f  /* 0.25 * log2(e) */

// ---------------- fp32 -> bf16 convert (weights) ----------------
__global__ __launch_bounds__(256) void cvt_kernel(const float* __restrict__ s,
                                                  short* __restrict__ d, int n2) {
  int i = blockIdx.x * 256 + threadIdx.x;
  if (i < n2) {
    float2 v = ((const float2*)s)[i];
    ((uint32_t*)d)[i] = pack2(v.x, v.y);
  }
}

// qkv weights: scale Q rows (n<128) by 0.25*log2e (score scale folded, log2 domain)
__global__ __launch_bounds__(256) void cvt_qkv_kernel(const float* __restrict__ s,
                                                      short* __restrict__ d) {
  int i = blockIdx.x * 256 + threadIdx.x;
  if (i < NL * 384 * 64) {
    const int within = i % (384 * 64);
    const float sc = (within < 128 * 64) ? QSCALE : 1.0f;
    float2 v = ((const float2*)s)[i];
    ((uint32_t*)d)[i] = pack2(v.x * sc, v.y * sc);
  }
}

__global__ __launch_bounds__(256) void scale_bq_kernel(const float* __restrict__ s,
                                                       float* __restrict__ d) {
  int i = blockIdx.x * 256 + threadIdx.x;
  if (i < NL * 384) {
    const float sc = ((i % 384) < 128) ? QSCALE : 1.0f;
    d[i] = s[i] * sc;
  }
}

// ---------------- transpose (S,B,D) -> (B,S,D): x0 fp32, h fp32, hb bf16 ----------------
__global__ __launch_bounds__(256) void transpose_kernel(const float* __restrict__ src,
                                                        float* __restrict__ x0,
                                                        float* __restrict__ h,
                                                        short* __restrict__ hb) {
  int f = blockIdx.x * 256 + threadIdx.x;
  int b = f >> 14;
  int rem = f & 16383;
  int s = rem >> 5;
  int d4 = rem & 31;
  const float4 v = ((const float4*)src)[((size_t)s * BB + b) * 32 + d4];
  ((float4*)x0)[f] = v;
  ((float4*)h)[f] = v;
  uint2 pb;
  pb.x = pack2(v.x, v.y);
  pb.y = pack2(v.z, v.w);
  ((uint2*)hb)[f] = pb;
}

// ---------------- per-row normalize -> bf16 ----------------
__global__ __launch_bounds__(256) void rownorm_kernel(const float* __restrict__ x,
                                                      short* __restrict__ xn) {
  const int wave = threadIdx.x >> 6;
  const int lane = threadIdx.x & 63;
  const size_t row = (size_t)blockIdx.x * 4 + wave;
  const float2 v = ((const float2*)(x + row * DD))[lane];
  float ss = v.x * v.x + v.y * v.y;
  #pragma unroll
  for (int off = 1; off < 64; off <<= 1) ss += __shfl_xor(ss, off);
  const float r = rsqrtf(ss);
  ((uint32_t*)xn)[row * 64 + lane] = pack2(v.x * r, v.y * r);
}

// ---------------- MFMA GEMM: C[m,n] = epilogue(sum_k A[m,k]*B[n,k]) ----------------
// MODE 0: + bias[n], optional ReLU.  MODE 1: max(.,1e-6).  MODE 2: clip(0.5*(max(.,1e-6)+prev),0.1,0.9)
// Register double-buffered staging (next k-tile loads overlap MFMAs).
template <int MODE, bool CBF, bool RELU>
__global__ __launch_bounds__(256) void mgemm(const short* __restrict__ Ab0,
                                             const short* __restrict__ Bw,
                                             const float* __restrict__ bias,
                                             void* __restrict__ Cp,
                                             int M, int N, int K,
                                             long sA, long sB, long sC) {
  __shared__ uint32_t Xs[128 * 32];
  __shared__ uint32_t Wls[128 * 32];
  const int t = threadIdx.x;
  const int wave = t >> 6, lane = t & 63;
  const int g = lane >> 4, p = lane & 15;
  const int wr = wave >> 1, wc = wave & 1;
  const int m0 = blockIdx.y * 128, n0 = blockIdx.x * 128;
  const int z = blockIdx.z;
  const short* Ab = Ab0 + (size_t)z * sA;
  const short* Bb = Bw + (size_t)z * sB;
  float* Cf = (float*)Cp + (CBF ? (size_t)0 : (size_t)z * sC);
  short* Cb = (short*)Cp;

  const int srow = t >> 3, skc = t & 7;   // staging row/col (x4 via +64 rows)

  f32x4 acc[4][4];
  #pragma unroll
  for (int i = 0; i < 4; ++i)
    #pragma unroll
    for (int j = 0; j < 4; ++j) acc[i][j] = (f32x4){0.f, 0.f, 0.f, 0.f};

  uint4 ra[4], rb[4];
  #pragma unroll
  for (int i = 0; i < 4; ++i) {
    const int row = srow + i * 32;
    ra[i] = *(const uint4*)(Ab + (size_t)(m0 + row) * K + skc * 8);
    rb[i] = *(const uint4*)(Bb + (size_t)(n0 + row) * K + skc * 8);
  }

  for (int kt = 0; kt < K; kt += 64) {
    __syncthreads();
    #pragma unroll
    for (int i = 0; i < 4; ++i) {
      const int row = srow + i * 32;
      *(uint4*)(Xs + row * 32 + ((skc ^ (row & 7)) << 2)) = ra[i];
      *(uint4*)(Wls + row * 32 + ((skc ^ (row & 7)) << 2)) = rb[i];
    }
    __syncthreads();
    if (kt + 64 < K) {
      #pragma unroll
      for (int i = 0; i < 4; ++i) {
        const int row = srow + i * 32;
        ra[i] = *(const uint4*)(Ab + (size_t)(m0 + row) * K + kt + 64 + skc * 8);
        rb[i] = *(const uint4*)(Bb + (size_t)(n0 + row) * K + kt + 64 + skc * 8);
      }
    }
    #pragma unroll
    for (int kc32 = 0; kc32 < 2; ++kc32) {
      bf16x8 xf[4], wf[4];
      #pragma unroll
      for (int mi = 0; mi < 4; ++mi) {
        const int row = wr * 64 + mi * 16 + p;
        union { bf16x8 v; uint4 w; } u;
        u.w = *(const uint4*)(Xs + row * 32 + (((kc32 * 4 + g) ^ (row & 7)) << 2));
        xf[mi] = u.v;
      }
      #pragma unroll
      for (int ni = 0; ni < 4; ++ni) {
        const int row = wc * 64 + ni * 16 + p;
        union { bf16x8 v; uint4 w; } u;
        u.w = *(const uint4*)(Wls + row * 32 + (((kc32 * 4 + g) ^ (row & 7)) << 2));
        wf[ni] = u.v;
      }
      #pragma unroll
      for (int mi = 0; mi < 4; ++mi)
        #pragma unroll
        for (int ni = 0; ni < 4; ++ni)
          acc[mi][ni] = __builtin_amdgcn_mfma_f32_16x16x32_bf16(wf[ni], xf[mi], acc[mi][ni], 0, 0, 0);
    }
  }

  #pragma unroll
  for (int mi = 0; mi < 4; ++mi) {
    const int m = m0 + wr * 64 + mi * 16 + p;
    #pragma unroll
    for (int ni = 0; ni < 4; ++ni) {
      const int nb = n0 + wc * 64 + ni * 16 + g * 4;
      float c[4];
      if (MODE == 0) {
        const float4 bv = *(const float4*)(bias + nb);
        const float bp[4] = {bv.x, bv.y, bv.z, bv.w};
        #pragma unroll
        for (int r = 0; r < 4; ++r) {
          c[r] = acc[mi][ni][r] + bp[r];
          if (RELU) c[r] = fmaxf(c[r], 0.0f);
        }
      } else if (MODE == 1) {
        #pragma unroll
        for (int r = 0; r < 4; ++r) c[r] = fmaxf(acc[mi][ni][r], 1e-6f);
      } else {
        const float4 pv = *(const float4*)(Cf + (size_t)m * N + nb);
        const float pp[4] = {pv.x, pv.y, pv.z, pv.w};
        #pragma unroll
        for (int r = 0; r < 4; ++r) {
          float v = fmaxf(acc[mi][ni][r], 1e-6f);
          c[r] = fminf(fmaxf(0.5f * (v + pp[r]), 0.1f), 0.9f);
        }
      }
      if (CBF) {
        uint2 w;
        w.x = pack2(c[0], c[1]);
        w.y = pack2(c[2], c[3]);
        *(uint2*)(Cb + (size_t)m * N + nb) = w;
      } else {
        float4 w;
        w.x = c[0]; w.y = c[1]; w.z = c[2]; w.w = c[3];
        *(float4*)(Cf + (size_t)m * N + nb) = w;
      }
    }
  }
}

// ---------------- MFMA GEMM (N=128) with fused residual+LayerNorm ----------------
template <int K>
__global__ __launch_bounds__(256) void mgemm_ln(const short* __restrict__ Ab,
                                                const short* __restrict__ Bw,
                                                const float* __restrict__ bias,
                                                float* __restrict__ hx,
                                                short* __restrict__ hb,
                                                const float* __restrict__ lng,
                                                const float* __restrict__ lnb) {
  __shared__ uint32_t Xs[128 * 32];
  __shared__ uint32_t Wls[128 * 32];
  const int t = threadIdx.x;
  const int wave = t >> 6, lane = t & 63;
  const int g = lane >> 4, p = lane & 15;
  const int wr = wave >> 1, wc = wave & 1;
  const int m0 = blockIdx.x * 128;

  const int srow = t >> 3, skc = t & 7;

  f32x4 acc[4][4];
  #pragma unroll
  for (int i = 0; i < 4; ++i)
    #pragma unroll
    for (int j = 0; j < 4; ++j) acc[i][j] = (f32x4){0.f, 0.f, 0.f, 0.f};

  uint4 ra[4], rb[4];
  #pragma unroll
  for (int i = 0; i < 4; ++i) {
    const int row = srow + i * 32;
    ra[i] = *(const uint4*)(Ab + (size_t)(m0 + row) * K + skc * 8);
    rb[i] = *(const uint4*)(Bw + (size_t)row * K + skc * 8);
  }

  for (int kt = 0; kt < K; kt += 64) {
    __syncthreads();
    #pragma unroll
    for (int i = 0; i < 4; ++i) {
      const int row = srow + i * 32;
      *(uint4*)(Xs + row * 32 + ((skc ^ (row & 7)) << 2)) = ra[i];
      *(uint4*)(Wls + row * 32 + ((skc ^ (row & 7)) << 2)) = rb[i];
    }
    __syncthreads();
    if (kt + 64 < K) {
      #pragma unroll
      for (int i = 0; i < 4; ++i) {
        const int row = srow + i * 32;
        ra[i] = *(const uint4*)(Ab + (size_t)(m0 + row) * K + kt + 64 + skc * 8);
        rb[i] = *(const uint4*)(Bw + (size_t)row * K + kt + 64 + skc * 8);
      }
    }
    #pragma unroll
    for (int kc32 = 0; kc32 < 2; ++kc32) {
      bf16x8 xf[4], wf[4];
      #pragma unroll
      for (int mi = 0; mi < 4; ++mi) {
        const int row = wr * 64 + mi * 16 + p;
        union { bf16x8 v; uint4 w; } u;
        u.w = *(const uint4*)(Xs + row * 32 + (((kc32 * 4 + g) ^ (row & 7)) << 2));
        xf[mi] = u.v;
      }
      #pragma unroll
      for (int ni = 0; ni < 4; ++ni) {
        const int row = wc * 64 + ni * 16 + p;
        union { bf16x8 v; uint4 w; } u;
        u.w = *(const uint4*)(Wls + row * 32 + (((kc32 * 4 + g) ^ (row & 7)) << 2));
        wf[ni] = u.v;
      }
      #pragma unroll
      for (int mi = 0; mi < 4; ++mi)
        #pragma unroll
        for (int ni = 0; ni < 4; ++ni)
          acc[mi][ni] = __builtin_amdgcn_mfma_f32_16x16x32_bf16(wf[ni], xf[mi], acc[mi][ni], 0, 0, 0);
    }
  }
  __syncthreads();

  float s1[4] = {0.f, 0.f, 0.f, 0.f};
  float s2[4] = {0.f, 0.f, 0.f, 0.f};
  #pragma unroll
  for (int mi = 0; mi < 4; ++mi) {
    const int m = m0 + wr * 64 + mi * 16 + p;
    #pragma unroll
    for (int ni = 0; ni < 4; ++ni) {
      const int nb = wc * 64 + ni * 16 + g * 4;
      const float4 rv = *(const float4*)(hx + (size_t)m * DD + nb);
      const float4 bv = *(const float4*)(bias + nb);
      acc[mi][ni][0] += bv.x + rv.x;
      acc[mi][ni][1] += bv.y + rv.y;
      acc[mi][ni][2] += bv.z + rv.z;
      acc[mi][ni][3] += bv.w + rv.w;
      #pragma unroll
      for (int r = 0; r < 4; ++r) {
        s1[mi] += acc[mi][ni][r];
        s2[mi] += acc[mi][ni][r] * acc[mi][ni][r];
      }
    }
  }
  float2* red = (float2*)Xs;
  #pragma unroll
  for (int mi = 0; mi < 4; ++mi) {
    const int lr = wr * 64 + mi * 16 + p;
    red[lr * 9 + wc * 4 + g] = make_float2(s1[mi], s2[mi]);
  }
  __syncthreads();
  #pragma unroll
  for (int mi = 0; mi < 4; ++mi) {
    const int lr = wr * 64 + mi * 16 + p;
    float a = 0.f, q = 0.f;
    #pragma unroll
    for (int sslot = 0; sslot < 8; ++sslot) {
      const float2 v = red[lr * 9 + sslot];
      a += v.x; q += v.y;
    }
    const float mu = a * (1.0f / 128.0f);
    const float rs = rsqrtf(fmaxf(q * (1.0f / 128.0f) - mu * mu, 0.0f) + 1e-5f);
    const int m = m0 + lr;
    #pragma unroll
    for (int ni = 0; ni < 4; ++ni) {
      const int nb = wc * 64 + ni * 16 + g * 4;
      const float4 gv = *(const float4*)(lng + nb);
      const float4 bv = *(const float4*)(lnb + nb);
      float c[4];
      c[0] = (acc[mi][ni][0] - mu) * rs * gv.x + bv.x;
      c[1] = (acc[mi][ni][1] - mu) * rs * gv.y + bv.y;
      c[2] = (acc[mi][ni][2] - mu) * rs * gv.z + bv.z;
      c[3] = (acc[mi][ni][3] - mu) * rs * gv.w + bv.w;
      float4 w;
      w.x = c[0]; w.y = c[1]; w.z = c[2]; w.w = c[3];
      *(float4*)(hx + (size_t)m * DD + nb) = w;
      uint2 wb;
      wb.x = pack2(c[0], c[1]);
      wb.y = pack2(c[2], c[3]);
      *(uint2*)(hb + (size_t)m * DD + nb) = wb;
    }
  }
}

// ---------------- MFMA flash attention v4 ----------------
// No max-tracking: scores are structurally bounded (|S_log2| <~ 15, fp32 exp2
// safe to 127), so P = exp2(S) directly; lsum reduce deferred to epilogue.
// Permuted K rows -> P lands in PV A-frag layout with zero shuffles.
// Two q-tiles per wave share K/V fragments.
__global__ __launch_bounds__(512) void attn_mfma_kernel(const short* __restrict__ qkv,
                                                        short* __restrict__ o_out) {
  const int h = blockIdx.x;
  const int b = blockIdx.y;
  const int z = blockIdx.z;
  const int t = threadIdx.x;
  const int wave = t >> 6;
  const int lane = t & 63;
  const int g = lane >> 4;
  const int p = lane & 15;

  __shared__ uint32_t Ks[512 * 8];   // 16 KB, swizzle: word ^= ((row>>3)&1)<<2
  __shared__ uint32_t Vs[16 * 256];  // 16 KB, V^T

  const short* base = qkv + (size_t)b * SS * 384;

  { // stage K
    const int row = t;
    const short* kp = base + (size_t)row * 384 + DD + h * HDIM;
    const uint4 lo = *(const uint4*)kp;
    const uint4 hi = *(const uint4*)(kp + 8);
    const int f = ((row >> 3) & 1) << 2;
    *(uint4*)(Ks + row * 8 + f) = lo;
    *(uint4*)(Ks + row * 8 + (f ^ 4)) = hi;
  }
  { // stage V^T (swizzled)
    const int k = t;
    const short* vp = base + (size_t)k * 384 + 2 * DD + h * HDIM;
    union { uint4 u[2]; short s[16]; } vv;
    vv.u[0] = *(const uint4*)vp;
    vv.u[1] = *(const uint4*)(vp + 8);
    const int wk = k >> 1;
    #pragma unroll
    for (int d = 0; d < 16; ++d) {
      const int word = d * 256 + (wk ^ ((d & 7) << 2));
      ((short*)(Vs + word))[k & 1] = vv.s[d];
    }
  }
  __syncthreads();

  const bf16x8 zfrag = {0, 0, 0, 0, 0, 0, 0, 0};
  const f32x4 zacc = {0.f, 0.f, 0.f, 0.f};

  // two q-tiles per wave
  const int qta = z * 16 + wave;
  const int qtb = qta + 8;
  bf16x8 qfa = zfrag, qfb = zfrag;
  if (g < 2) {
    union { bf16x8 v; uint4 w; } qu;
    qu.w = *(const uint4*)(base + (size_t)(qta * 16 + p) * 384 + h * HDIM + g * 8);
    qfa = qu.v;
    qu.w = *(const uint4*)(base + (size_t)(qtb * 16 + p) * 384 + h * HDIM + g * 8);
    qfb = qu.v;
  }

  f32x4 oa = zacc, ob = zacc;
  float lsa = 0.0f, lsb = 0.0f;

  for (int kv = 0; kv < 16; ++kv) {  // 32 keys per iteration
    bf16x8 ka = zfrag, kb = zfrag;
    if (g < 2) {
      const int r0 = kv * 32 + 8 * (p >> 2) + (p & 3);
      const int r1 = r0 + 4;
      union { bf16x8 v; uint4 w; } u;
      u.w = *(const uint4*)(Ks + r0 * 8 + ((4 * g) ^ (((r0 >> 3) & 1) << 2)));
      ka = u.v;
      u.w = *(const uint4*)(Ks + r1 * 8 + ((4 * g) ^ (((r1 >> 3) & 1) << 2)));
      kb = u.v;
    }
    union { bf16x8 v; uint4 w; } vu;
    vu.w = *(const uint4*)(Vs + p * 256 + ((kv * 16 + g * 4) ^ ((p & 7) << 2)));

    // lane (g,p): s0[r] = S[q=p][key kv*32+8g+r], s1[r] = key kv*32+8g+4+r
    const f32x4 s0a = __builtin_amdgcn_mfma_f32_16x16x32_bf16(ka, qfa, zacc, 0, 0, 0);
    const f32x4 s1a = __builtin_amdgcn_mfma_f32_16x16x32_bf16(kb, qfa, zacc, 0, 0, 0);
    const f32x4 s0b = __builtin_amdgcn_mfma_f32_16x16x32_bf16(ka, qfb, zacc, 0, 0, 0);
    const f32x4 s1b = __builtin_amdgcn_mfma_f32_16x16x32_bf16(kb, qfb, zacc, 0, 0, 0);

    float va0[4], va1[4], vb0[4], vb1[4];
    #pragma unroll
    for (int r = 0; r < 4; ++r) {
      va0[r] = __builtin_amdgcn_exp2f(s0a[r]);
      va1[r] = __builtin_amdgcn_exp2f(s1a[r]);
      vb0[r] = __builtin_amdgcn_exp2f(s0b[r]);
      vb1[r] = __builtin_amdgcn_exp2f(s1b[r]);
    }
    #pragma unroll
    for (int r = 0; r < 4; ++r) {
      lsa += va0[r] + va1[r];
      lsb += vb0[r] + vb1[r];
    }

    union { bf16x8 v; uint4 w; } pa, pb;
    pa.w.x = pack2(va0[0], va0[1]);
    pa.w.y = pack2(va0[2], va0[3]);
    pa.w.z = pack2(va1[0], va1[1]);
    pa.w.w = pack2(va1[2], va1[3]);
    pb.w.x = pack2(vb0[0], vb0[1]);
    pb.w.y = pack2(vb0[2], vb0[3]);
    pb.w.z = pack2(vb1[0], vb1[1]);
    pb.w.w = pack2(vb1[2], vb1[3]);

    oa = __builtin_amdgcn_mfma_f32_16x16x32_bf16(pa.v, vu.v, oa, 0, 0, 0);
    ob = __builtin_amdgcn_mfma_f32_16x16x32_bf16(pb.v, vu.v, ob, 0, 0, 0);
  }

  // reduce lsum across g (lanes differing in bits 4,5)
  lsa += __shfl_xor(lsa, 16); lsa += __shfl_xor(lsa, 32);
  lsb += __shfl_xor(lsb, 16); lsb += __shfl_xor(lsb, 32);
  const float lia = 1.0f / lsa;
  const float lib = 1.0f / lsb;
  #pragma unroll
  for (int r = 0; r < 4; ++r) {
    const float inva = __shfl(lia, 4 * g + r);
    const float invb = __shfl(lib, 4 * g + r);
    o_out[((size_t)(b * SS + qta * 16 + 4 * g + r)) * DD + h * HDIM + p] =
        (short)(pack2(oa[r] * inva, 0.0f) & 0xffff);
    o_out[((size_t)(b * SS + qtb * 16 + 4 * g + r)) * DD + h * HDIM + p] =
        (short)(pack2(ob[r] * invb, 0.0f) & 0xffff);
  }
}

// ---------------- yn = normalize(sigmoid(h) * x0) rowwise -> bf16 ----------------
__global__ __launch_bounds__(256) void mask_norm_kernel(const float* __restrict__ h,
                                                        const float* __restrict__ x0,
                                                        short* __restrict__ yn) {
  const int wave = threadIdx.x >> 6;
  const int lane = threadIdx.x & 63;
  const size_t row = (size_t)blockIdx.x * 4 + wave;
  const float2 hv = ((const float2*)(h + row * DD))[lane];
  const float2 xv = ((const float2*)(x0 + row * DD))[lane];
  const float a = xv.x / (1.0f + __expf(-hv.x));
  const float c = xv.y / (1.0f + __expf(-hv.y));
  float ss = a * a + c * c;
  #pragma unroll
  for (int off = 1; off < 64; off <<= 1) ss += __shfl_xor(ss, off);
  const float inv = 1.0f / fmaxf(sqrtf(ss), 1e-12f);
  ((uint32_t*)yn)[row * 64 + lane] = pack2(a * inv, c * inv);
}

extern "C" void kernel_launch(void* const* d_in, const int* in_sizes, int n_in,
                              void* d_out, int out_size, void* d_ws, size_t ws_size,
                              hipStream_t stream) {
  const float* src  = (const float*)d_in[0];
  const float* Wqkv = (const float*)d_in[1];
  const float* bqkv = (const float*)d_in[2];
  const float* Wo   = (const float*)d_in[3];
  const float* bo   = (const float*)d_in[4];
  const float* ln1g = (const float*)d_in[5];
  const float* ln1b = (const float*)d_in[6];
  const float* W1   = (const float*)d_in[7];
  const float* b1   = (const float*)d_in[8];
  const float* W2   = (const float*)d_in[9];
  const float* b2   = (const float*)d_in[10];
  const float* ln2g = (const float*)d_in[11];
  const float* ln2b = (const float*)d_in[12];
  float* out = (float*)d_out;

  char* W = (char*)d_ws;
  const size_t MB = 1048576;
  float* x0  = (float*)(W);
  float* h   = (float*)(W + 16 * MB);
  short* hb  = (short*)(W + 32 * MB);
  short* qkv = (short*)(W + 40 * MB);
  short* ff1 = (short*)(W + 64 * MB);
  short* att = (short*)(W + 128 * MB);
  short* xn  = (short*)(W + 136 * MB);
  short* yn  = (short*)(W + 144 * MB);
  short* wqB = (short*)(W + 152 * MB);
  short* woB = wqB + (size_t)NL * 384 * DD;
  short* w1B = woB + (size_t)NL * DD * DD;
  short* w2B = w1B + (size_t)NL * FFD * DD;
  float* bq2 = (float*)(w2B + (size_t)NL * DD * FFD);

  const dim3 blk(256);
  const int ROWS = BB * SS;

  cvt_qkv_kernel<<<(NL * 384 * 64 + 255) / 256, blk, 0, stream>>>(Wqkv, wqB);
  cvt_kernel<<<(NL * DD * DD / 2 + 255) / 256, blk, 0, stream>>>(Wo, woB, NL * DD * DD / 2);
  cvt_kernel<<<(NL * FFD * DD / 2 + 255) / 256, blk, 0, stream>>>(W1, w1B, NL * FFD * DD / 2);
  cvt_kernel<<<(NL * DD * FFD / 2 + 255) / 256, blk, 0, stream>>>(W2, w2B, NL * DD * FFD / 2);
  scale_bq_kernel<<<(NL * 384 + 255) / 256, blk, 0, stream>>>(bqkv, bq2);

  transpose_kernel<<<4096, blk, 0, stream>>>(src, x0, h, hb);
  rownorm_kernel<<<ROWS / 4, blk, 0, stream>>>(x0, xn);
  mgemm<1, false, false><<<dim3(4, 4, BB), blk, 0, stream>>>(
      xn, xn, nullptr, out, SS, SS, DD, (long)SS * DD, (long)SS * DD, (long)SS * SS);

  for (int l = 0; l < NL; ++l) {
    mgemm<0, true, false><<<dim3(3, ROWS / 128, 1), blk, 0, stream>>>(
        hb, wqB + (size_t)l * 384 * DD, bq2 + l * 384, qkv, ROWS, 384, DD, 0, 0, 0);
    attn_mfma_kernel<<<dim3(HH, BB, 2), dim3(512), 0, stream>>>(qkv, att);
    mgemm_ln<DD><<<dim3(ROWS / 128), blk, 0, stream>>>(
        att, woB + (size_t)l * DD * DD, bo + l * DD, h, hb, ln1g + l * DD, ln1b + l * DD);
    mgemm<0, true, true><<<dim3(8, ROWS / 128, 1), blk, 0, stream>>>(
        hb, w1B + (size_t)l * FFD * DD, b1 + l * FFD, ff1, ROWS, FFD, DD, 0, 0, 0);
    mgemm_ln<FFD><<<dim3(ROWS / 128), blk, 0, stream>>>(
        ff1, w2B + (size_t)l * DD * FFD, b2 + l * DD, h, hb, ln2g + l * DD, ln2b + l * DD);
  }

  mask_norm_kernel<<<ROWS / 4, blk, 0, stream>>>(h, x0, yn);
  mgemm<2, false, false><<<dim3(4, 4, BB), blk, 0, stream>>>(
      yn, yn, nullptr, out, SS, SS, DD, (long)SS * DD, (long)SS * DD, (long)SS * SS);
}

// Round 7
// 1011.317 us; speedup vs baseline: 1.4940x; 1.4940x over previous
//
#include <hip/hip_runtime.h>
#include <cstdint>
#include <cstddef>

#define SS 512
#define BB 64
#define DD 128
#define HH 8
#define HDIM 16
#define FFD 1024
#define NL 6

typedef short bf16x8 __attribute__((ext_vector_type(8)));
typedef float f32x4 __attribute__((ext_vector_type(4)));

// hardware packed f32->bf16 (RNE), low16 = a, high16 = b
__device__ inline uint32_t pack2(float a, float b) {
  uint32_t r;
  asm("v_cvt_pk_bf16_f32 %0, %1, %2" : "=v"(r) : "v"(a), "v"(b));
  return r;
}

#define QSCALE 0.36067376022224085f  /* 0.25 * log2(e) */

// ---------------- fp32 -> bf16 convert (weights) ----------------
__global__ __launch_bounds__(256) void cvt_kernel(const float* __restrict__ s,
                                                  short* __restrict__ d, int n2) {
  int i = blockIdx.x * 256 + threadIdx.x;
  if (i < n2) {
    float2 v = ((const float2*)s)[i];
    ((uint32_t*)d)[i] = pack2(v.x, v.y);
  }
}

// qkv weights: scale Q rows (n<128) by 0.25*log2e (score scale folded, log2 domain)
__global__ __launch_bounds__(256) void cvt_qkv_kernel(const float* __restrict__ s,
                                                      short* __restrict__ d) {
  int i = blockIdx.x * 256 + threadIdx.x;
  if (i < NL * 384 * 64) {
    const int within = i % (384 * 64);
    const float sc = (within < 128 * 64) ? QSCALE : 1.0f;
    float2 v = ((const float2*)s)[i];
    ((uint32_t*)d)[i] = pack2(v.x * sc, v.y * sc);
  }
}

__global__ __launch_bounds__(256) void scale_bq_kernel(const float* __restrict__ s,
                                                       float* __restrict__ d) {
  int i = blockIdx.x * 256 + threadIdx.x;
  if (i < NL * 384) {
    const float sc = ((i % 384) < 128) ? QSCALE : 1.0f;
    d[i] = s[i] * sc;
  }
}

// ---------------- transpose (S,B,D) -> (B,S,D): x0 fp32, h fp32, hb bf16 ----------------
__global__ __launch_bounds__(256) void transpose_kernel(const float* __restrict__ src,
                                                        float* __restrict__ x0,
                                                        float* __restrict__ h,
                                                        short* __restrict__ hb) {
  int f = blockIdx.x * 256 + threadIdx.x;
  int b = f >> 14;
  int rem = f & 16383;
  int s = rem >> 5;
  int d4 = rem & 31;
  const float4 v = ((const float4*)src)[((size_t)s * BB + b) * 32 + d4];
  ((float4*)x0)[f] = v;
  ((float4*)h)[f] = v;
  uint2 pb;
  pb.x = pack2(v.x, v.y);
  pb.y = pack2(v.z, v.w);
  ((uint2*)hb)[f] = pb;
}

// ---------------- per-row normalize -> bf16 ----------------
__global__ __launch_bounds__(256) void rownorm_kernel(const float* __restrict__ x,
                                                      short* __restrict__ xn) {
  const int wave = threadIdx.x >> 6;
  const int lane = threadIdx.x & 63;
  const size_t row = (size_t)blockIdx.x * 4 + wave;
  const float2 v = ((const float2*)(x + row * DD))[lane];
  float ss = v.x * v.x + v.y * v.y;
  #pragma unroll
  for (int off = 1; off < 64; off <<= 1) ss += __shfl_xor(ss, off);
  const float r = rsqrtf(ss);
  ((uint32_t*)xn)[row * 64 + lane] = pack2(v.x * r, v.y * r);
}

// ---------------- MFMA GEMM: C[m,n] = epilogue(sum_k A[m,k]*B[n,k]) ----------------
// MODE 0: + bias[n], optional ReLU.  MODE 1: max(.,1e-6).  MODE 2: clip(0.5*(max(.,1e-6)+prev),0.1,0.9)
// NOTE: no register prefetch — reg double-buffer spilled to scratch (r6: WRITE_SIZE 3x, occupancy 19%).
template <int MODE, bool CBF, bool RELU>
__global__ __launch_bounds__(256) void mgemm(const short* __restrict__ Ab0,
                                             const short* __restrict__ Bw,
                                             const float* __restrict__ bias,
                                             void* __restrict__ Cp,
                                             int M, int N, int K,
                                             long sA, long sB, long sC) {
  __shared__ uint32_t Xs[128 * 32];
  __shared__ uint32_t Wls[128 * 32];
  const int t = threadIdx.x;
  const int wave = t >> 6, lane = t & 63;
  const int g = lane >> 4, p = lane & 15;
  const int wr = wave >> 1, wc = wave & 1;
  const int m0 = blockIdx.y * 128, n0 = blockIdx.x * 128;
  const int z = blockIdx.z;
  const short* Ab = Ab0 + (size_t)z * sA;
  const short* Bb = Bw + (size_t)z * sB;
  float* Cf = (float*)Cp + (CBF ? (size_t)0 : (size_t)z * sC);
  short* Cb = (short*)Cp;

  f32x4 acc[4][4];
  #pragma unroll
  for (int i = 0; i < 4; ++i)
    #pragma unroll
    for (int j = 0; j < 4; ++j) acc[i][j] = (f32x4){0.f, 0.f, 0.f, 0.f};

  for (int kt = 0; kt < K; kt += 64) {
    __syncthreads();
    #pragma unroll
    for (int i = 0; i < 4; ++i) {
      const int idx = t + i * 256;
      const int row = idx >> 3, kc = idx & 7;
      const uint4 w = *(const uint4*)(Ab + (size_t)(m0 + row) * K + kt + kc * 8);
      *(uint4*)(Xs + row * 32 + ((kc ^ (row & 7)) << 2)) = w;
      const uint4 u = *(const uint4*)(Bb + (size_t)(n0 + row) * K + kt + kc * 8);
      *(uint4*)(Wls + row * 32 + ((kc ^ (row & 7)) << 2)) = u;
    }
    __syncthreads();
    #pragma unroll
    for (int kc32 = 0; kc32 < 2; ++kc32) {
      bf16x8 xf[4], wf[4];
      #pragma unroll
      for (int mi = 0; mi < 4; ++mi) {
        const int row = wr * 64 + mi * 16 + p;
        union { bf16x8 v; uint4 w; } u;
        u.w = *(const uint4*)(Xs + row * 32 + (((kc32 * 4 + g) ^ (row & 7)) << 2));
        xf[mi] = u.v;
      }
      #pragma unroll
      for (int ni = 0; ni < 4; ++ni) {
        const int row = wc * 64 + ni * 16 + p;
        union { bf16x8 v; uint4 w; } u;
        u.w = *(const uint4*)(Wls + row * 32 + (((kc32 * 4 + g) ^ (row & 7)) << 2));
        wf[ni] = u.v;
      }
      #pragma unroll
      for (int mi = 0; mi < 4; ++mi)
        #pragma unroll
        for (int ni = 0; ni < 4; ++ni)
          acc[mi][ni] = __builtin_amdgcn_mfma_f32_16x16x32_bf16(wf[ni], xf[mi], acc[mi][ni], 0, 0, 0);
    }
  }

  #pragma unroll
  for (int mi = 0; mi < 4; ++mi) {
    const int m = m0 + wr * 64 + mi * 16 + p;
    #pragma unroll
    for (int ni = 0; ni < 4; ++ni) {
      const int nb = n0 + wc * 64 + ni * 16 + g * 4;
      float c[4];
      if (MODE == 0) {
        const float4 bv = *(const float4*)(bias + nb);
        const float bp[4] = {bv.x, bv.y, bv.z, bv.w};
        #pragma unroll
        for (int r = 0; r < 4; ++r) {
          c[r] = acc[mi][ni][r] + bp[r];
          if (RELU) c[r] = fmaxf(c[r], 0.0f);
        }
      } else if (MODE == 1) {
        #pragma unroll
        for (int r = 0; r < 4; ++r) c[r] = fmaxf(acc[mi][ni][r], 1e-6f);
      } else {
        const float4 pv = *(const float4*)(Cf + (size_t)m * N + nb);
        const float pp[4] = {pv.x, pv.y, pv.z, pv.w};
        #pragma unroll
        for (int r = 0; r < 4; ++r) {
          float v = fmaxf(acc[mi][ni][r], 1e-6f);
          c[r] = fminf(fmaxf(0.5f * (v + pp[r]), 0.1f), 0.9f);
        }
      }
      if (CBF) {
        uint2 w;
        w.x = pack2(c[0], c[1]);
        w.y = pack2(c[2], c[3]);
        *(uint2*)(Cb + (size_t)m * N + nb) = w;
      } else {
        float4 w;
        w.x = c[0]; w.y = c[1]; w.z = c[2]; w.w = c[3];
        *(float4*)(Cf + (size_t)m * N + nb) = w;
      }
    }
  }
}

// ---------------- MFMA GEMM (N=128) with fused residual+LayerNorm ----------------
template <int K>
__global__ __launch_bounds__(256) void mgemm_ln(const short* __restrict__ Ab,
                                                const short* __restrict__ Bw,
                                                const float* __restrict__ bias,
                                                float* __restrict__ hx,
                                                short* __restrict__ hb,
                                                const float* __restrict__ lng,
                                                const float* __restrict__ lnb) {
  __shared__ uint32_t Xs[128 * 32];
  __shared__ uint32_t Wls[128 * 32];
  const int t = threadIdx.x;
  const int wave = t >> 6, lane = t & 63;
  const int g = lane >> 4, p = lane & 15;
  const int wr = wave >> 1, wc = wave & 1;
  const int m0 = blockIdx.x * 128;

  f32x4 acc[4][4];
  #pragma unroll
  for (int i = 0; i < 4; ++i)
    #pragma unroll
    for (int j = 0; j < 4; ++j) acc[i][j] = (f32x4){0.f, 0.f, 0.f, 0.f};

  for (int kt = 0; kt < K; kt += 64) {
    __syncthreads();
    #pragma unroll
    for (int i = 0; i < 4; ++i) {
      const int idx = t + i * 256;
      const int row = idx >> 3, kc = idx & 7;
      const uint4 w = *(const uint4*)(Ab + (size_t)(m0 + row) * K + kt + kc * 8);
      *(uint4*)(Xs + row * 32 + ((kc ^ (row & 7)) << 2)) = w;
      const uint4 u = *(const uint4*)(Bw + (size_t)row * K + kt + kc * 8);
      *(uint4*)(Wls + row * 32 + ((kc ^ (row & 7)) << 2)) = u;
    }
    __syncthreads();
    #pragma unroll
    for (int kc32 = 0; kc32 < 2; ++kc32) {
      bf16x8 xf[4], wf[4];
      #pragma unroll
      for (int mi = 0; mi < 4; ++mi) {
        const int row = wr * 64 + mi * 16 + p;
        union { bf16x8 v; uint4 w; } u;
        u.w = *(const uint4*)(Xs + row * 32 + (((kc32 * 4 + g) ^ (row & 7)) << 2));
        xf[mi] = u.v;
      }
      #pragma unroll
      for (int ni = 0; ni < 4; ++ni) {
        const int row = wc * 64 + ni * 16 + p;
        union { bf16x8 v; uint4 w; } u;
        u.w = *(const uint4*)(Wls + row * 32 + (((kc32 * 4 + g) ^ (row & 7)) << 2));
        wf[ni] = u.v;
      }
      #pragma unroll
      for (int mi = 0; mi < 4; ++mi)
        #pragma unroll
        for (int ni = 0; ni < 4; ++ni)
          acc[mi][ni] = __builtin_amdgcn_mfma_f32_16x16x32_bf16(wf[ni], xf[mi], acc[mi][ni], 0, 0, 0);
    }
  }
  __syncthreads();

  float s1[4] = {0.f, 0.f, 0.f, 0.f};
  float s2[4] = {0.f, 0.f, 0.f, 0.f};
  #pragma unroll
  for (int mi = 0; mi < 4; ++mi) {
    const int m = m0 + wr * 64 + mi * 16 + p;
    #pragma unroll
    for (int ni = 0; ni < 4; ++ni) {
      const int nb = wc * 64 + ni * 16 + g * 4;
      const float4 rv = *(const float4*)(hx + (size_t)m * DD + nb);
      const float4 bv = *(const float4*)(bias + nb);
      acc[mi][ni][0] += bv.x + rv.x;
      acc[mi][ni][1] += bv.y + rv.y;
      acc[mi][ni][2] += bv.z + rv.z;
      acc[mi][ni][3] += bv.w + rv.w;
      #pragma unroll
      for (int r = 0; r < 4; ++r) {
        s1[mi] += acc[mi][ni][r];
        s2[mi] += acc[mi][ni][r] * acc[mi][ni][r];
      }
    }
  }
  float2* red = (float2*)Xs;
  #pragma unroll
  for (int mi = 0; mi < 4; ++mi) {
    const int lr = wr * 64 + mi * 16 + p;
    red[lr * 9 + wc * 4 + g] = make_float2(s1[mi], s2[mi]);
  }
  __syncthreads();
  #pragma unroll
  for (int mi = 0; mi < 4; ++mi) {
    const int lr = wr * 64 + mi * 16 + p;
    float a = 0.f, q = 0.f;
    #pragma unroll
    for (int sslot = 0; sslot < 8; ++sslot) {
      const float2 v = red[lr * 9 + sslot];
      a += v.x; q += v.y;
    }
    const float mu = a * (1.0f / 128.0f);
    const float rs = rsqrtf(fmaxf(q * (1.0f / 128.0f) - mu * mu, 0.0f) + 1e-5f);
    const int m = m0 + lr;
    #pragma unroll
    for (int ni = 0; ni < 4; ++ni) {
      const int nb = wc * 64 + ni * 16 + g * 4;
      const float4 gv = *(const float4*)(lng + nb);
      const float4 bv = *(const float4*)(lnb + nb);
      float c[4];
      c[0] = (acc[mi][ni][0] - mu) * rs * gv.x + bv.x;
      c[1] = (acc[mi][ni][1] - mu) * rs * gv.y + bv.y;
      c[2] = (acc[mi][ni][2] - mu) * rs * gv.z + bv.z;
      c[3] = (acc[mi][ni][3] - mu) * rs * gv.w + bv.w;
      float4 w;
      w.x = c[0]; w.y = c[1]; w.z = c[2]; w.w = c[3];
      *(float4*)(hx + (size_t)m * DD + nb) = w;
      uint2 wb;
      wb.x = pack2(c[0], c[1]);
      wb.y = pack2(c[2], c[3]);
      *(uint2*)(hb + (size_t)m * DD + nb) = wb;
    }
  }
}

// ---------------- MFMA flash attention v4 ----------------
// No max-tracking: scores are structurally bounded (|S_log2| <~ 15, fp32 exp2
// safe to 127), so P = exp2(S) directly; lsum reduce deferred to epilogue.
// Permuted K rows -> P lands in PV A-frag layout with zero shuffles.
// Two q-tiles per wave share K/V fragments.
__global__ __launch_bounds__(512) void attn_mfma_kernel(const short* __restrict__ qkv,
                                                        short* __restrict__ o_out) {
  const int h = blockIdx.x;
  const int b = blockIdx.y;
  const int z = blockIdx.z;
  const int t = threadIdx.x;
  const int wave = t >> 6;
  const int lane = t & 63;
  const int g = lane >> 4;
  const int p = lane & 15;

  __shared__ uint32_t Ks[512 * 8];   // 16 KB, swizzle: word ^= ((row>>3)&1)<<2
  __shared__ uint32_t Vs[16 * 256];  // 16 KB, V^T

  const short* base = qkv + (size_t)b * SS * 384;

  { // stage K
    const int row = t;
    const short* kp = base + (size_t)row * 384 + DD + h * HDIM;
    const uint4 lo = *(const uint4*)kp;
    const uint4 hi = *(const uint4*)(kp + 8);
    const int f = ((row >> 3) & 1) << 2;
    *(uint4*)(Ks + row * 8 + f) = lo;
    *(uint4*)(Ks + row * 8 + (f ^ 4)) = hi;
  }
  { // stage V^T (swizzled)
    const int k = t;
    const short* vp = base + (size_t)k * 384 + 2 * DD + h * HDIM;
    union { uint4 u[2]; short s[16]; } vv;
    vv.u[0] = *(const uint4*)vp;
    vv.u[1] = *(const uint4*)(vp + 8);
    const int wk = k >> 1;
    #pragma unroll
    for (int d = 0; d < 16; ++d) {
      const int word = d * 256 + (wk ^ ((d & 7) << 2));
      ((short*)(Vs + word))[k & 1] = vv.s[d];
    }
  }
  __syncthreads();

  const bf16x8 zfrag = {0, 0, 0, 0, 0, 0, 0, 0};
  const f32x4 zacc = {0.f, 0.f, 0.f, 0.f};

  // two q-tiles per wave
  const int qta = z * 16 + wave;
  const int qtb = qta + 8;
  bf16x8 qfa = zfrag, qfb = zfrag;
  if (g < 2) {
    union { bf16x8 v; uint4 w; } qu;
    qu.w = *(const uint4*)(base + (size_t)(qta * 16 + p) * 384 + h * HDIM + g * 8);
    qfa = qu.v;
    qu.w = *(const uint4*)(base + (size_t)(qtb * 16 + p) * 384 + h * HDIM + g * 8);
    qfb = qu.v;
  }

  f32x4 oa = zacc, ob = zacc;
  float lsa = 0.0f, lsb = 0.0f;

  for (int kv = 0; kv < 16; ++kv) {  // 32 keys per iteration
    bf16x8 ka = zfrag, kb = zfrag;
    if (g < 2) {
      const int r0 = kv * 32 + 8 * (p >> 2) + (p & 3);
      const int r1 = r0 + 4;
      union { bf16x8 v; uint4 w; } u;
      u.w = *(const uint4*)(Ks + r0 * 8 + ((4 * g) ^ (((r0 >> 3) & 1) << 2)));
      ka = u.v;
      u.w = *(const uint4*)(Ks + r1 * 8 + ((4 * g) ^ (((r1 >> 3) & 1) << 2)));
      kb = u.v;
    }
    union { bf16x8 v; uint4 w; } vu;
    vu.w = *(const uint4*)(Vs + p * 256 + ((kv * 16 + g * 4) ^ ((p & 7) << 2)));

    // lane (g,p): s0[r] = S[q=p][key kv*32+8g+r], s1[r] = key kv*32+8g+4+r
    const f32x4 s0a = __builtin_amdgcn_mfma_f32_16x16x32_bf16(ka, qfa, zacc, 0, 0, 0);
    const f32x4 s1a = __builtin_amdgcn_mfma_f32_16x16x32_bf16(kb, qfa, zacc, 0, 0, 0);
    const f32x4 s0b = __builtin_amdgcn_mfma_f32_16x16x32_bf16(ka, qfb, zacc, 0, 0, 0);
    const f32x4 s1b = __builtin_amdgcn_mfma_f32_16x16x32_bf16(kb, qfb, zacc, 0, 0, 0);

    float va0[4], va1[4], vb0[4], vb1[4];
    #pragma unroll
    for (int r = 0; r < 4; ++r) {
      va0[r] = __builtin_amdgcn_exp2f(s0a[r]);
      va1[r] = __builtin_amdgcn_exp2f(s1a[r]);
      vb0[r] = __builtin_amdgcn_exp2f(s0b[r]);
      vb1[r] = __builtin_amdgcn_exp2f(s1b[r]);
    }
    #pragma unroll
    for (int r = 0; r < 4; ++r) {
      lsa += va0[r] + va1[r];
      lsb += vb0[r] + vb1[r];
    }

    union { bf16x8 v; uint4 w; } pa, pb;
    pa.w.x = pack2(va0[0], va0[1]);
    pa.w.y = pack2(va0[2], va0[3]);
    pa.w.z = pack2(va1[0], va1[1]);
    pa.w.w = pack2(va1[2], va1[3]);
    pb.w.x = pack2(vb0[0], vb0[1]);
    pb.w.y = pack2(vb0[2], vb0[3]);
    pb.w.z = pack2(vb1[0], vb1[1]);
    pb.w.w = pack2(vb1[2], vb1[3]);

    oa = __builtin_amdgcn_mfma_f32_16x16x32_bf16(pa.v, vu.v, oa, 0, 0, 0);
    ob = __builtin_amdgcn_mfma_f32_16x16x32_bf16(pb.v, vu.v, ob, 0, 0, 0);
  }

  // reduce lsum across g (lanes differing in bits 4,5)
  lsa += __shfl_xor(lsa, 16); lsa += __shfl_xor(lsa, 32);
  lsb += __shfl_xor(lsb, 16); lsb += __shfl_xor(lsb, 32);
  const float lia = 1.0f / lsa;
  const float lib = 1.0f / lsb;
  #pragma unroll
  for (int r = 0; r < 4; ++r) {
    const float inva = __shfl(lia, 4 * g + r);
    const float invb = __shfl(lib, 4 * g + r);
    o_out[((size_t)(b * SS + qta * 16 + 4 * g + r)) * DD + h * HDIM + p] =
        (short)(pack2(oa[r] * inva, 0.0f) & 0xffff);
    o_out[((size_t)(b * SS + qtb * 16 + 4 * g + r)) * DD + h * HDIM + p] =
        (short)(pack2(ob[r] * invb, 0.0f) & 0xffff);
  }
}

// ---------------- yn = normalize(sigmoid(h) * x0) rowwise -> bf16 ----------------
__global__ __launch_bounds__(256) void mask_norm_kernel(const float* __restrict__ h,
                                                        const float* __restrict__ x0,
                                                        short* __restrict__ yn) {
  const int wave = threadIdx.x >> 6;
  const int lane = threadIdx.x & 63;
  const size_t row = (size_t)blockIdx.x * 4 + wave;
  const float2 hv = ((const float2*)(h + row * DD))[lane];
  const float2 xv = ((const float2*)(x0 + row * DD))[lane];
  const float a = xv.x / (1.0f + __expf(-hv.x));
  const float c = xv.y / (1.0f + __expf(-hv.y));
  float ss = a * a + c * c;
  #pragma unroll
  for (int off = 1; off < 64; off <<= 1) ss += __shfl_xor(ss, off);
  const float inv = 1.0f / fmaxf(sqrtf(ss), 1e-12f);
  ((uint32_t*)yn)[row * 64 + lane] = pack2(a * inv, c * inv);
}

extern "C" void kernel_launch(void* const* d_in, const int* in_sizes, int n_in,
                              void* d_out, int out_size, void* d_ws, size_t ws_size,
                              hipStream_t stream) {
  const float* src  = (const float*)d_in[0];
  const float* Wqkv = (const float*)d_in[1];
  const float* bqkv = (const float*)d_in[2];
  const float* Wo   = (const float*)d_in[3];
  const float* bo   = (const float*)d_in[4];
  const float* ln1g = (const float*)d_in[5];
  const float* ln1b = (const float*)d_in[6];
  const float* W1   = (const float*)d_in[7];
  const float* b1   = (const float*)d_in[8];
  const float* W2   = (const float*)d_in[9];
  const float* b2   = (const float*)d_in[10];
  const float* ln2g = (const float*)d_in[11];
  const float* ln2b = (const float*)d_in[12];
  float* out = (float*)d_out;

  char* W = (char*)d_ws;
  const size_t MB = 1048576;
  float* x0  = (float*)(W);
  float* h   = (float*)(W + 16 * MB);
  short* hb  = (short*)(W + 32 * MB);
  short* qkv = (short*)(W + 40 * MB);
  short* ff1 = (short*)(W + 64 * MB);
  short* att = (short*)(W + 128 * MB);
  short* xn  = (short*)(W + 136 * MB);
  short* yn  = (short*)(W + 144 * MB);
  short* wqB = (short*)(W + 152 * MB);
  short* woB = wqB + (size_t)NL * 384 * DD;
  short* w1B = woB + (size_t)NL * DD * DD;
  short* w2B = w1B + (size_t)NL * FFD * DD;
  float* bq2 = (float*)(w2B + (size_t)NL * DD * FFD);

  const dim3 blk(256);
  const int ROWS = BB * SS;

  cvt_qkv_kernel<<<(NL * 384 * 64 + 255) / 256, blk, 0, stream>>>(Wqkv, wqB);
  cvt_kernel<<<(NL * DD * DD / 2 + 255) / 256, blk, 0, stream>>>(Wo, woB, NL * DD * DD / 2);
  cvt_kernel<<<(NL * FFD * DD / 2 + 255) / 256, blk, 0, stream>>>(W1, w1B, NL * FFD * DD / 2);
  cvt_kernel<<<(NL * DD * FFD / 2 + 255) / 256, blk, 0, stream>>>(W2, w2B, NL * DD * FFD / 2);
  scale_bq_kernel<<<(NL * 384 + 255) / 256, blk, 0, stream>>>(bqkv, bq2);

  transpose_kernel<<<4096, blk, 0, stream>>>(src, x0, h, hb);
  rownorm_kernel<<<ROWS / 4, blk, 0, stream>>>(x0, xn);
  mgemm<1, false, false><<<dim3(4, 4, BB), blk, 0, stream>>>(
      xn, xn, nullptr, out, SS, SS, DD, (long)SS * DD, (long)SS * DD, (long)SS * SS);

  for (int l = 0; l < NL; ++l) {
    mgemm<0, true, false><<<dim3(3, ROWS / 128, 1), blk, 0, stream>>>(
        hb, wqB + (size_t)l * 384 * DD, bq2 + l * 384, qkv, ROWS, 384, DD, 0, 0, 0);
    attn_mfma_kernel<<<dim3(HH, BB, 2), dim3(512), 0, stream>>>(qkv, att);
    mgemm_ln<DD><<<dim3(ROWS / 128), blk, 0, stream>>>(
        att, woB + (size_t)l * DD * DD, bo + l * DD, h, hb, ln1g + l * DD, ln1b + l * DD);
    mgemm<0, true, true><<<dim3(8, ROWS / 128, 1), blk, 0, stream>>>(
        hb, w1B + (size_t)l * FFD * DD, b1 + l * FFD, ff1, ROWS, FFD, DD, 0, 0, 0);
    mgemm_ln<FFD><<<dim3(ROWS / 128), blk, 0, stream>>>(
        ff1, w2B + (size_t)l * DD * FFD, b2 + l * DD, h, hb, ln2g + l * DD, ln2b + l * DD);
  }

  mask_norm_kernel<<<ROWS / 4, blk, 0, stream>>>(h, x0, yn);
  mgemm<2, false, false><<<dim3(4, 4, BB), blk, 0, stream>>>(
      yn, yn, nullptr, out, SS, SS, DD, (long)SS * DD, (long)SS * DD, (long)SS * SS);
}

// Round 8
// 898.735 us; speedup vs baseline: 1.6811x; 1.1253x over previous
//
#include <hip/hip_runtime.h>
#include <cstdint>
#include <cstddef>

#define SS 512
#define BB 64
#define DD 128
#define HH 8
#define HDIM 16
#define FFD 1024
#define NL 6

typedef short bf16x8 __attribute__((ext_vector_type(8)));
typedef float f32x4 __attribute__((ext_vector_type(4)));

// hardware packed f32->bf16 (RNE), low16 = a, high16 = b
__device__ inline uint32_t pack2(float a, float b) {
  uint32_t r;
  asm("v_cvt_pk_bf16_f32 %0, %1, %2" : "=v"(r) : "v"(a), "v"(b));
  return r;
}

#define QSCALE 0.36067376022224085f  /* 0.25 * log2(e) */

// ---------------- fp32 -> bf16 convert (weights) ----------------
__global__ __launch_bounds__(256) void cvt_kernel(const float* __restrict__ s,
                                                  short* __restrict__ d, int n2) {
  int i = blockIdx.x * 256 + threadIdx.x;
  if (i < n2) {
    float2 v = ((const float2*)s)[i];
    ((uint32_t*)d)[i] = pack2(v.x, v.y);
  }
}

// qkv weights: scale Q rows (n<128) by 0.25*log2e (score scale folded, log2 domain)
__global__ __launch_bounds__(256) void cvt_qkv_kernel(const float* __restrict__ s,
                                                      short* __restrict__ d) {
  int i = blockIdx.x * 256 + threadIdx.x;
  if (i < NL * 384 * 64) {
    const int within = i % (384 * 64);
    const float sc = (within < 128 * 64) ? QSCALE : 1.0f;
    float2 v = ((const float2*)s)[i];
    ((uint32_t*)d)[i] = pack2(v.x * sc, v.y * sc);
  }
}

__global__ __launch_bounds__(256) void scale_bq_kernel(const float* __restrict__ s,
                                                       float* __restrict__ d) {
  int i = blockIdx.x * 256 + threadIdx.x;
  if (i < NL * 384) {
    const float sc = ((i % 384) < 128) ? QSCALE : 1.0f;
    d[i] = s[i] * sc;
  }
}

// ---------------- transpose (S,B,D) -> (B,S,D): x0 fp32, h fp32, hb bf16 ----------------
__global__ __launch_bounds__(256) void transpose_kernel(const float* __restrict__ src,
                                                        float* __restrict__ x0,
                                                        float* __restrict__ h,
                                                        short* __restrict__ hb) {
  int f = blockIdx.x * 256 + threadIdx.x;
  int b = f >> 14;
  int rem = f & 16383;
  int s = rem >> 5;
  int d4 = rem & 31;
  const float4 v = ((const float4*)src)[((size_t)s * BB + b) * 32 + d4];
  ((float4*)x0)[f] = v;
  ((float4*)h)[f] = v;
  uint2 pb;
  pb.x = pack2(v.x, v.y);
  pb.y = pack2(v.z, v.w);
  ((uint2*)hb)[f] = pb;
}

// ---------------- per-row normalize -> bf16 ----------------
__global__ __launch_bounds__(256) void rownorm_kernel(const float* __restrict__ x,
                                                      short* __restrict__ xn) {
  const int wave = threadIdx.x >> 6;
  const int lane = threadIdx.x & 63;
  const size_t row = (size_t)blockIdx.x * 4 + wave;
  const float2 v = ((const float2*)(x + row * DD))[lane];
  float ss = v.x * v.x + v.y * v.y;
  #pragma unroll
  for (int off = 1; off < 64; off <<= 1) ss += __shfl_xor(ss, off);
  const float r = rsqrtf(ss);
  ((uint32_t*)xn)[row * 64 + lane] = pack2(v.x * r, v.y * r);
}

// ---------------- MFMA GEMM: C[m,n] = epilogue(sum_k A[m,k]*B[n,k]) ----------------
// MODE 0: + bias[n], optional ReLU.  MODE 1: max(.,1e-6).  MODE 2: clip(0.5*(max(.,1e-6)+prev),0.1,0.9)
// NOTE: no register prefetch — reg double-buffer spilled to scratch (r6: WRITE_SIZE 3x, occupancy 19%).
template <int MODE, bool CBF, bool RELU>
__global__ __launch_bounds__(256) void mgemm(const short* __restrict__ Ab0,
                                             const short* __restrict__ Bw,
                                             const float* __restrict__ bias,
                                             void* __restrict__ Cp,
                                             int M, int N, int K,
                                             long sA, long sB, long sC) {
  __shared__ uint32_t Xs[128 * 32];
  __shared__ uint32_t Wls[128 * 32];
  const int t = threadIdx.x;
  const int wave = t >> 6, lane = t & 63;
  const int g = lane >> 4, p = lane & 15;
  const int wr = wave >> 1, wc = wave & 1;
  const int m0 = blockIdx.y * 128, n0 = blockIdx.x * 128;
  const int z = blockIdx.z;
  const short* Ab = Ab0 + (size_t)z * sA;
  const short* Bb = Bw + (size_t)z * sB;
  float* Cf = (float*)Cp + (CBF ? (size_t)0 : (size_t)z * sC);
  short* Cb = (short*)Cp;

  f32x4 acc[4][4];
  #pragma unroll
  for (int i = 0; i < 4; ++i)
    #pragma unroll
    for (int j = 0; j < 4; ++j) acc[i][j] = (f32x4){0.f, 0.f, 0.f, 0.f};

  for (int kt = 0; kt < K; kt += 64) {
    __syncthreads();
    #pragma unroll
    for (int i = 0; i < 4; ++i) {
      const int idx = t + i * 256;
      const int row = idx >> 3, kc = idx & 7;
      const uint4 w = *(const uint4*)(Ab + (size_t)(m0 + row) * K + kt + kc * 8);
      *(uint4*)(Xs + row * 32 + ((kc ^ (row & 7)) << 2)) = w;
      const uint4 u = *(const uint4*)(Bb + (size_t)(n0 + row) * K + kt + kc * 8);
      *(uint4*)(Wls + row * 32 + ((kc ^ (row & 7)) << 2)) = u;
    }
    __syncthreads();
    #pragma unroll
    for (int kc32 = 0; kc32 < 2; ++kc32) {
      bf16x8 xf[4], wf[4];
      #pragma unroll
      for (int mi = 0; mi < 4; ++mi) {
        const int row = wr * 64 + mi * 16 + p;
        union { bf16x8 v; uint4 w; } u;
        u.w = *(const uint4*)(Xs + row * 32 + (((kc32 * 4 + g) ^ (row & 7)) << 2));
        xf[mi] = u.v;
      }
      #pragma unroll
      for (int ni = 0; ni < 4; ++ni) {
        const int row = wc * 64 + ni * 16 + p;
        union { bf16x8 v; uint4 w; } u;
        u.w = *(const uint4*)(Wls + row * 32 + (((kc32 * 4 + g) ^ (row & 7)) << 2));
        wf[ni] = u.v;
      }
      #pragma unroll
      for (int mi = 0; mi < 4; ++mi)
        #pragma unroll
        for (int ni = 0; ni < 4; ++ni)
          acc[mi][ni] = __builtin_amdgcn_mfma_f32_16x16x32_bf16(wf[ni], xf[mi], acc[mi][ni], 0, 0, 0);
    }
  }

  #pragma unroll
  for (int mi = 0; mi < 4; ++mi) {
    const int m = m0 + wr * 64 + mi * 16 + p;
    #pragma unroll
    for (int ni = 0; ni < 4; ++ni) {
      const int nb = n0 + wc * 64 + ni * 16 + g * 4;
      float c[4];
      if (MODE == 0) {
        const float4 bv = *(const float4*)(bias + nb);
        const float bp[4] = {bv.x, bv.y, bv.z, bv.w};
        #pragma unroll
        for (int r = 0; r < 4; ++r) {
          c[r] = acc[mi][ni][r] + bp[r];
          if (RELU) c[r] = fmaxf(c[r], 0.0f);
        }
      } else if (MODE == 1) {
        #pragma unroll
        for (int r = 0; r < 4; ++r) c[r] = fmaxf(acc[mi][ni][r], 1e-6f);
      } else {
        const float4 pv = *(const float4*)(Cf + (size_t)m * N + nb);
        const float pp[4] = {pv.x, pv.y, pv.z, pv.w};
        #pragma unroll
        for (int r = 0; r < 4; ++r) {
          float v = fmaxf(acc[mi][ni][r], 1e-6f);
          c[r] = fminf(fmaxf(0.5f * (v + pp[r]), 0.1f), 0.9f);
        }
      }
      if (CBF) {
        uint2 w;
        w.x = pack2(c[0], c[1]);
        w.y = pack2(c[2], c[3]);
        *(uint2*)(Cb + (size_t)m * N + nb) = w;
      } else {
        float4 w;
        w.x = c[0]; w.y = c[1]; w.z = c[2]; w.w = c[3];
        *(float4*)(Cf + (size_t)m * N + nb) = w;
      }
    }
  }
}

// ---------------- MFMA GEMM (N=128) with fused residual+LayerNorm ----------------
template <int K>
__global__ __launch_bounds__(256) void mgemm_ln(const short* __restrict__ Ab,
                                                const short* __restrict__ Bw,
                                                const float* __restrict__ bias,
                                                float* __restrict__ hx,
                                                short* __restrict__ hb,
                                                const float* __restrict__ lng,
                                                const float* __restrict__ lnb) {
  __shared__ uint32_t Xs[128 * 32];
  __shared__ uint32_t Wls[128 * 32];
  const int t = threadIdx.x;
  const int wave = t >> 6, lane = t & 63;
  const int g = lane >> 4, p = lane & 15;
  const int wr = wave >> 1, wc = wave & 1;
  const int m0 = blockIdx.x * 128;

  f32x4 acc[4][4];
  #pragma unroll
  for (int i = 0; i < 4; ++i)
    #pragma unroll
    for (int j = 0; j < 4; ++j) acc[i][j] = (f32x4){0.f, 0.f, 0.f, 0.f};

  for (int kt = 0; kt < K; kt += 64) {
    __syncthreads();
    #pragma unroll
    for (int i = 0; i < 4; ++i) {
      const int idx = t + i * 256;
      const int row = idx >> 3, kc = idx & 7;
      const uint4 w = *(const uint4*)(Ab + (size_t)(m0 + row) * K + kt + kc * 8);
      *(uint4*)(Xs + row * 32 + ((kc ^ (row & 7)) << 2)) = w;
      const uint4 u = *(const uint4*)(Bw + (size_t)row * K + kt + kc * 8);
      *(uint4*)(Wls + row * 32 + ((kc ^ (row & 7)) << 2)) = u;
    }
    __syncthreads();
    #pragma unroll
    for (int kc32 = 0; kc32 < 2; ++kc32) {
      bf16x8 xf[4], wf[4];
      #pragma unroll
      for (int mi = 0; mi < 4; ++mi) {
        const int row = wr * 64 + mi * 16 + p;
        union { bf16x8 v; uint4 w; } u;
        u.w = *(const uint4*)(Xs + row * 32 + (((kc32 * 4 + g) ^ (row & 7)) << 2));
        xf[mi] = u.v;
      }
      #pragma unroll
      for (int ni = 0; ni < 4; ++ni) {
        const int row = wc * 64 + ni * 16 + p;
        union { bf16x8 v; uint4 w; } u;
        u.w = *(const uint4*)(Wls + row * 32 + (((kc32 * 4 + g) ^ (row & 7)) << 2));
        wf[ni] = u.v;
      }
      #pragma unroll
      for (int mi = 0; mi < 4; ++mi)
        #pragma unroll
        for (int ni = 0; ni < 4; ++ni)
          acc[mi][ni] = __builtin_amdgcn_mfma_f32_16x16x32_bf16(wf[ni], xf[mi], acc[mi][ni], 0, 0, 0);
    }
  }
  __syncthreads();

  float s1[4] = {0.f, 0.f, 0.f, 0.f};
  float s2[4] = {0.f, 0.f, 0.f, 0.f};
  #pragma unroll
  for (int mi = 0; mi < 4; ++mi) {
    const int m = m0 + wr * 64 + mi * 16 + p;
    #pragma unroll
    for (int ni = 0; ni < 4; ++ni) {
      const int nb = wc * 64 + ni * 16 + g * 4;
      const float4 rv = *(const float4*)(hx + (size_t)m * DD + nb);
      const float4 bv = *(const float4*)(bias + nb);
      acc[mi][ni][0] += bv.x + rv.x;
      acc[mi][ni][1] += bv.y + rv.y;
      acc[mi][ni][2] += bv.z + rv.z;
      acc[mi][ni][3] += bv.w + rv.w;
      #pragma unroll
      for (int r = 0; r < 4; ++r) {
        s1[mi] += acc[mi][ni][r];
        s2[mi] += acc[mi][ni][r] * acc[mi][ni][r];
      }
    }
  }
  float2* red = (float2*)Xs;
  #pragma unroll
  for (int mi = 0; mi < 4; ++mi) {
    const int lr = wr * 64 + mi * 16 + p;
    red[lr * 9 + wc * 4 + g] = make_float2(s1[mi], s2[mi]);
  }
  __syncthreads();
  #pragma unroll
  for (int mi = 0; mi < 4; ++mi) {
    const int lr = wr * 64 + mi * 16 + p;
    float a = 0.f, q = 0.f;
    #pragma unroll
    for (int sslot = 0; sslot < 8; ++sslot) {
      const float2 v = red[lr * 9 + sslot];
      a += v.x; q += v.y;
    }
    const float mu = a * (1.0f / 128.0f);
    const float rs = rsqrtf(fmaxf(q * (1.0f / 128.0f) - mu * mu, 0.0f) + 1e-5f);
    const int m = m0 + lr;
    #pragma unroll
    for (int ni = 0; ni < 4; ++ni) {
      const int nb = wc * 64 + ni * 16 + g * 4;
      const float4 gv = *(const float4*)(lng + nb);
      const float4 bv = *(const float4*)(lnb + nb);
      float c[4];
      c[0] = (acc[mi][ni][0] - mu) * rs * gv.x + bv.x;
      c[1] = (acc[mi][ni][1] - mu) * rs * gv.y + bv.y;
      c[2] = (acc[mi][ni][2] - mu) * rs * gv.z + bv.z;
      c[3] = (acc[mi][ni][3] - mu) * rs * gv.w + bv.w;
      float4 w;
      w.x = c[0]; w.y = c[1]; w.z = c[2]; w.w = c[3];
      *(float4*)(hx + (size_t)m * DD + nb) = w;
      uint2 wb;
      wb.x = pack2(c[0], c[1]);
      wb.y = pack2(c[2], c[3]);
      *(uint2*)(hb + (size_t)m * DD + nb) = wb;
    }
  }
}

// ---------------- MFMA flash attention v5 ----------------
// Single q-tile per iteration (v3's register footprint — v4's 2-tile version
// spilled: VGPR 128, WRITE_SIZE 63MB) + no max-tracking (v4's simplification:
// scores structurally bounded, exp2 direct, lsum reduced once after kv loop).
// Permuted K rows -> P lands in PV A-frag layout with zero shuffles.
__global__ __launch_bounds__(512) void attn_mfma_kernel(const short* __restrict__ qkv,
                                                        short* __restrict__ o_out) {
  const int h = blockIdx.x;
  const int b = blockIdx.y;
  const int z = blockIdx.z;
  const int t = threadIdx.x;
  const int wave = t >> 6;
  const int lane = t & 63;
  const int g = lane >> 4;
  const int p = lane & 15;

  __shared__ uint32_t Ks[512 * 8];   // 16 KB, swizzle: word ^= ((row>>3)&1)<<2
  __shared__ uint32_t Vs[16 * 256];  // 16 KB, V^T

  const short* base = qkv + (size_t)b * SS * 384;

  { // stage K
    const int row = t;
    const short* kp = base + (size_t)row * 384 + DD + h * HDIM;
    const uint4 lo = *(const uint4*)kp;
    const uint4 hi = *(const uint4*)(kp + 8);
    const int f = ((row >> 3) & 1) << 2;
    *(uint4*)(Ks + row * 8 + f) = lo;
    *(uint4*)(Ks + row * 8 + (f ^ 4)) = hi;
  }
  { // stage V^T (swizzled)
    const int k = t;
    const short* vp = base + (size_t)k * 384 + 2 * DD + h * HDIM;
    union { uint4 u[2]; short s[16]; } vv;
    vv.u[0] = *(const uint4*)vp;
    vv.u[1] = *(const uint4*)(vp + 8);
    const int wk = k >> 1;
    #pragma unroll
    for (int d = 0; d < 16; ++d) {
      const int word = d * 256 + (wk ^ ((d & 7) << 2));
      ((short*)(Vs + word))[k & 1] = vv.s[d];
    }
  }
  __syncthreads();

  const bf16x8 zfrag = {0, 0, 0, 0, 0, 0, 0, 0};
  const f32x4 zacc = {0.f, 0.f, 0.f, 0.f};

  #pragma unroll
  for (int qi = 0; qi < 2; ++qi) {
    const int qt = z * 16 + wave + qi * 8;
    bf16x8 qf = zfrag;
    if (g < 2) {
      union { bf16x8 v; uint4 w; } qu;
      qu.w = *(const uint4*)(base + (size_t)(qt * 16 + p) * 384 + h * HDIM + g * 8);
      qf = qu.v;
    }

    f32x4 o = zacc;
    float lsum = 0.0f;

    for (int kv = 0; kv < 16; ++kv) {  // 32 keys per iteration
      bf16x8 ka = zfrag, kb = zfrag;
      if (g < 2) {
        const int r0 = kv * 32 + 8 * (p >> 2) + (p & 3);
        const int r1 = r0 + 4;
        union { bf16x8 v; uint4 w; } u;
        u.w = *(const uint4*)(Ks + r0 * 8 + ((4 * g) ^ (((r0 >> 3) & 1) << 2)));
        ka = u.v;
        u.w = *(const uint4*)(Ks + r1 * 8 + ((4 * g) ^ (((r1 >> 3) & 1) << 2)));
        kb = u.v;
      }
      union { bf16x8 v; uint4 w; } vu;
      vu.w = *(const uint4*)(Vs + p * 256 + ((kv * 16 + g * 4) ^ ((p & 7) << 2)));

      // lane (g,p): s0[r] = S[q=p][key kv*32+8g+r], s1[r] = key kv*32+8g+4+r
      const f32x4 s0 = __builtin_amdgcn_mfma_f32_16x16x32_bf16(ka, qf, zacc, 0, 0, 0);
      const f32x4 s1 = __builtin_amdgcn_mfma_f32_16x16x32_bf16(kb, qf, zacc, 0, 0, 0);

      float sv0[4], sv1[4];
      #pragma unroll
      for (int r = 0; r < 4; ++r) {
        sv0[r] = __builtin_amdgcn_exp2f(s0[r]);
        sv1[r] = __builtin_amdgcn_exp2f(s1[r]);
      }
      #pragma unroll
      for (int r = 0; r < 4; ++r) lsum += sv0[r] + sv1[r];

      union { bf16x8 v; uint4 w; } pu;
      pu.w.x = pack2(sv0[0], sv0[1]);
      pu.w.y = pack2(sv0[2], sv0[3]);
      pu.w.z = pack2(sv1[0], sv1[1]);
      pu.w.w = pack2(sv1[2], sv1[3]);

      o = __builtin_amdgcn_mfma_f32_16x16x32_bf16(pu.v, vu.v, o, 0, 0, 0);
    }

    // reduce lsum across g (lanes differing in bits 4,5); lane (g,p): q=p
    lsum += __shfl_xor(lsum, 16);
    lsum += __shfl_xor(lsum, 32);
    const float li = 1.0f / lsum;
    #pragma unroll
    for (int r = 0; r < 4; ++r) {
      const float inv = __shfl(li, 4 * g + r);
      o_out[((size_t)(b * SS + qt * 16 + 4 * g + r)) * DD + h * HDIM + p] =
          (short)(pack2(o[r] * inv, 0.0f) & 0xffff);
    }
  }
}

// ---------------- yn = normalize(sigmoid(h) * x0) rowwise -> bf16 ----------------
__global__ __launch_bounds__(256) void mask_norm_kernel(const float* __restrict__ h,
                                                        const float* __restrict__ x0,
                                                        short* __restrict__ yn) {
  const int wave = threadIdx.x >> 6;
  const int lane = threadIdx.x & 63;
  const size_t row = (size_t)blockIdx.x * 4 + wave;
  const float2 hv = ((const float2*)(h + row * DD))[lane];
  const float2 xv = ((const float2*)(x0 + row * DD))[lane];
  const float a = xv.x / (1.0f + __expf(-hv.x));
  const float c = xv.y / (1.0f + __expf(-hv.y));
  float ss = a * a + c * c;
  #pragma unroll
  for (int off = 1; off < 64; off <<= 1) ss += __shfl_xor(ss, off);
  const float inv = 1.0f / fmaxf(sqrtf(ss), 1e-12f);
  ((uint32_t*)yn)[row * 64 + lane] = pack2(a * inv, c * inv);
}

extern "C" void kernel_launch(void* const* d_in, const int* in_sizes, int n_in,
                              void* d_out, int out_size, void* d_ws, size_t ws_size,
                              hipStream_t stream) {
  const float* src  = (const float*)d_in[0];
  const float* Wqkv = (const float*)d_in[1];
  const float* bqkv = (const float*)d_in[2];
  const float* Wo   = (const float*)d_in[3];
  const float* bo   = (const float*)d_in[4];
  const float* ln1g = (const float*)d_in[5];
  const float* ln1b = (const float*)d_in[6];
  const float* W1   = (const float*)d_in[7];
  const float* b1   = (const float*)d_in[8];
  const float* W2   = (const float*)d_in[9];
  const float* b2   = (const float*)d_in[10];
  const float* ln2g = (const float*)d_in[11];
  const float* ln2b = (const float*)d_in[12];
  float* out = (float*)d_out;

  char* W = (char*)d_ws;
  const size_t MB = 1048576;
  float* x0  = (float*)(W);
  float* h   = (float*)(W + 16 * MB);
  short* hb  = (short*)(W + 32 * MB);
  short* qkv = (short*)(W + 40 * MB);
  short* ff1 = (short*)(W + 64 * MB);
  short* att = (short*)(W + 128 * MB);
  short* xn  = (short*)(W + 136 * MB);
  short* yn  = (short*)(W + 144 * MB);
  short* wqB = (short*)(W + 152 * MB);
  short* woB = wqB + (size_t)NL * 384 * DD;
  short* w1B = woB + (size_t)NL * DD * DD;
  short* w2B = w1B + (size_t)NL * FFD * DD;
  float* bq2 = (float*)(w2B + (size_t)NL * DD * FFD);

  const dim3 blk(256);
  const int ROWS = BB * SS;

  cvt_qkv_kernel<<<(NL * 384 * 64 + 255) / 256, blk, 0, stream>>>(Wqkv, wqB);
  cvt_kernel<<<(NL * DD * DD / 2 + 255) / 256, blk, 0, stream>>>(Wo, woB, NL * DD * DD / 2);
  cvt_kernel<<<(NL * FFD * DD / 2 + 255) / 256, blk, 0, stream>>>(W1, w1B, NL * FFD * DD / 2);
  cvt_kernel<<<(NL * DD * FFD / 2 + 255) / 256, blk, 0, stream>>>(W2, w2B, NL * DD * FFD / 2);
  scale_bq_kernel<<<(NL * 384 + 255) / 256, blk, 0, stream>>>(bqkv, bq2);

  transpose_kernel<<<4096, blk, 0, stream>>>(src, x0, h, hb);
  rownorm_kernel<<<ROWS / 4, blk, 0, stream>>>(x0, xn);
  mgemm<1, false, false><<<dim3(4, 4, BB), blk, 0, stream>>>(
      xn, xn, nullptr, out, SS, SS, DD, (long)SS * DD, (long)SS * DD, (long)SS * SS);

  for (int l = 0; l < NL; ++l) {
    mgemm<0, true, false><<<dim3(3, ROWS / 128, 1), blk, 0, stream>>>(
        hb, wqB + (size_t)l * 384 * DD, bq2 + l * 384, qkv, ROWS, 384, DD, 0, 0, 0);
    attn_mfma_kernel<<<dim3(HH, BB, 2), dim3(512), 0, stream>>>(qkv, att);
    mgemm_ln<DD><<<dim3(ROWS / 128), blk, 0, stream>>>(
        att, woB + (size_t)l * DD * DD, bo + l * DD, h, hb, ln1g + l * DD, ln1b + l * DD);
    mgemm<0, true, true><<<dim3(8, ROWS / 128, 1), blk, 0, stream>>>(
        hb, w1B + (size_t)l * FFD * DD, b1 + l * FFD, ff1, ROWS, FFD, DD, 0, 0, 0);
    mgemm_ln<FFD><<<dim3(ROWS / 128), blk, 0, stream>>>(
        ff1, w2B + (size_t)l * DD * FFD, b2 + l * DD, h, hb, ln2g + l * DD, ln2b + l * DD);
  }

  mask_norm_kernel<<<ROWS / 4, blk, 0, stream>>>(h, x0, yn);
  mgemm<2, false, false><<<dim3(4, 4, BB), blk, 0, stream>>>(
      yn, yn, nullptr, out, SS, SS, DD, (long)SS * DD, (long)SS * DD, (long)SS * SS);
}

// Round 9
// 749.810 us; speedup vs baseline: 2.0150x; 1.1986x over previous
//
#include <hip/hip_runtime.h>
#include <cstdint>
#include <cstddef>

#define SS 512
#define BB 64
#define DD 128
#define HH 8
#define HDIM 16
#define FFD 1024
#define NL 6

typedef short bf16x8 __attribute__((ext_vector_type(8)));
typedef float f32x4 __attribute__((ext_vector_type(4)));

// hardware packed f32->bf16 (RNE), low16 = a, high16 = b
__device__ inline uint32_t pack2(float a, float b) {
  uint32_t r;
  asm("v_cvt_pk_bf16_f32 %0, %1, %2" : "=v"(r) : "v"(a), "v"(b));
  return r;
}

#define QSCALE 0.36067376022224085f  /* 0.25 * log2(e) */

// ---------------- fp32 -> bf16 convert (weights) ----------------
__global__ __launch_bounds__(256) void cvt_kernel(const float* __restrict__ s,
                                                  short* __restrict__ d, int n2) {
  int i = blockIdx.x * 256 + threadIdx.x;
  if (i < n2) {
    float2 v = ((const float2*)s)[i];
    ((uint32_t*)d)[i] = pack2(v.x, v.y);
  }
}

// qkv weights: scale Q rows (n<128) by 0.25*log2e (score scale folded, log2 domain)
__global__ __launch_bounds__(256) void cvt_qkv_kernel(const float* __restrict__ s,
                                                      short* __restrict__ d) {
  int i = blockIdx.x * 256 + threadIdx.x;
  if (i < NL * 384 * 64) {
    const int within = i % (384 * 64);
    const float sc = (within < 128 * 64) ? QSCALE : 1.0f;
    float2 v = ((const float2*)s)[i];
    ((uint32_t*)d)[i] = pack2(v.x * sc, v.y * sc);
  }
}

__global__ __launch_bounds__(256) void scale_bq_kernel(const float* __restrict__ s,
                                                       float* __restrict__ d) {
  int i = blockIdx.x * 256 + threadIdx.x;
  if (i < NL * 384) {
    const float sc = ((i % 384) < 128) ? QSCALE : 1.0f;
    d[i] = s[i] * sc;
  }
}

// ---------------- transpose (S,B,D) -> (B,S,D): x0 fp32, h fp32, hb bf16 ----------------
__global__ __launch_bounds__(256) void transpose_kernel(const float* __restrict__ src,
                                                        float* __restrict__ x0,
                                                        float* __restrict__ h,
                                                        short* __restrict__ hb) {
  int f = blockIdx.x * 256 + threadIdx.x;
  int b = f >> 14;
  int rem = f & 16383;
  int s = rem >> 5;
  int d4 = rem & 31;
  const float4 v = ((const float4*)src)[((size_t)s * BB + b) * 32 + d4];
  ((float4*)x0)[f] = v;
  ((float4*)h)[f] = v;
  uint2 pb;
  pb.x = pack2(v.x, v.y);
  pb.y = pack2(v.z, v.w);
  ((uint2*)hb)[f] = pb;
}

// ---------------- per-row normalize -> bf16 ----------------
__global__ __launch_bounds__(256) void rownorm_kernel(const float* __restrict__ x,
                                                      short* __restrict__ xn) {
  const int wave = threadIdx.x >> 6;
  const int lane = threadIdx.x & 63;
  const size_t row = (size_t)blockIdx.x * 4 + wave;
  const float2 v = ((const float2*)(x + row * DD))[lane];
  float ss = v.x * v.x + v.y * v.y;
  #pragma unroll
  for (int off = 1; off < 64; off <<= 1) ss += __shfl_xor(ss, off);
  const float r = rsqrtf(ss);
  ((uint32_t*)xn)[row * 64 + lane] = pack2(v.x * r, v.y * r);
}

// ---------------- MFMA GEMM: C[m,n] = epilogue(sum_k A[m,k]*B[n,k]) ----------------
// MODE 0: + bias[n], optional ReLU.  MODE 1: max(.,1e-6).  MODE 2: clip(0.5*(max(.,1e-6)+prev),0.1,0.9)
template <int MODE, bool CBF, bool RELU>
__global__ __launch_bounds__(256) void mgemm(const short* __restrict__ Ab0,
                                             const short* __restrict__ Bw,
                                             const float* __restrict__ bias,
                                             void* __restrict__ Cp,
                                             int M, int N, int K,
                                             long sA, long sB, long sC) {
  __shared__ uint32_t Xs[128 * 32];
  __shared__ uint32_t Wls[128 * 32];
  const int t = threadIdx.x;
  const int wave = t >> 6, lane = t & 63;
  const int g = lane >> 4, p = lane & 15;
  const int wr = wave >> 1, wc = wave & 1;
  const int m0 = blockIdx.y * 128, n0 = blockIdx.x * 128;
  const int z = blockIdx.z;
  const short* Ab = Ab0 + (size_t)z * sA;
  const short* Bb = Bw + (size_t)z * sB;
  float* Cf = (float*)Cp + (CBF ? (size_t)0 : (size_t)z * sC);
  short* Cb = (short*)Cp;

  f32x4 acc[4][4];
  #pragma unroll
  for (int i = 0; i < 4; ++i)
    #pragma unroll
    for (int j = 0; j < 4; ++j) acc[i][j] = (f32x4){0.f, 0.f, 0.f, 0.f};

  for (int kt = 0; kt < K; kt += 64) {
    __syncthreads();
    #pragma unroll
    for (int i = 0; i < 4; ++i) {
      const int idx = t + i * 256;
      const int row = idx >> 3, kc = idx & 7;
      const uint4 w = *(const uint4*)(Ab + (size_t)(m0 + row) * K + kt + kc * 8);
      *(uint4*)(Xs + row * 32 + ((kc ^ (row & 7)) << 2)) = w;
      const uint4 u = *(const uint4*)(Bb + (size_t)(n0 + row) * K + kt + kc * 8);
      *(uint4*)(Wls + row * 32 + ((kc ^ (row & 7)) << 2)) = u;
    }
    __syncthreads();
    #pragma unroll
    for (int kc32 = 0; kc32 < 2; ++kc32) {
      bf16x8 xf[4], wf[4];
      #pragma unroll
      for (int mi = 0; mi < 4; ++mi) {
        const int row = wr * 64 + mi * 16 + p;
        union { bf16x8 v; uint4 w; } u;
        u.w = *(const uint4*)(Xs + row * 32 + (((kc32 * 4 + g) ^ (row & 7)) << 2));
        xf[mi] = u.v;
      }
      #pragma unroll
      for (int ni = 0; ni < 4; ++ni) {
        const int row = wc * 64 + ni * 16 + p;
        union { bf16x8 v; uint4 w; } u;
        u.w = *(const uint4*)(Wls + row * 32 + (((kc32 * 4 + g) ^ (row & 7)) << 2));
        wf[ni] = u.v;
      }
      #pragma unroll
      for (int mi = 0; mi < 4; ++mi)
        #pragma unroll
        for (int ni = 0; ni < 4; ++ni)
          acc[mi][ni] = __builtin_amdgcn_mfma_f32_16x16x32_bf16(wf[ni], xf[mi], acc[mi][ni], 0, 0, 0);
    }
  }

  #pragma unroll
  for (int mi = 0; mi < 4; ++mi) {
    const int m = m0 + wr * 64 + mi * 16 + p;
    #pragma unroll
    for (int ni = 0; ni < 4; ++ni) {
      const int nb = n0 + wc * 64 + ni * 16 + g * 4;
      float c[4];
      if (MODE == 0) {
        const float4 bv = *(const float4*)(bias + nb);
        const float bp[4] = {bv.x, bv.y, bv.z, bv.w};
        #pragma unroll
        for (int r = 0; r < 4; ++r) {
          c[r] = acc[mi][ni][r] + bp[r];
          if (RELU) c[r] = fmaxf(c[r], 0.0f);
        }
      } else if (MODE == 1) {
        #pragma unroll
        for (int r = 0; r < 4; ++r) c[r] = fmaxf(acc[mi][ni][r], 1e-6f);
      } else {
        const float4 pv = *(const float4*)(Cf + (size_t)m * N + nb);
        const float pp[4] = {pv.x, pv.y, pv.z, pv.w};
        #pragma unroll
        for (int r = 0; r < 4; ++r) {
          float v = fmaxf(acc[mi][ni][r], 1e-6f);
          c[r] = fminf(fmaxf(0.5f * (v + pp[r]), 0.1f), 0.9f);
        }
      }
      if (CBF) {
        uint2 w;
        w.x = pack2(c[0], c[1]);
        w.y = pack2(c[2], c[3]);
        *(uint2*)(Cb + (size_t)m * N + nb) = w;
      } else {
        float4 w;
        w.x = c[0]; w.y = c[1]; w.z = c[2]; w.w = c[3];
        *(float4*)(Cf + (size_t)m * N + nb) = w;
      }
    }
  }
}

// ---------------- MFMA GEMM (N=128) with fused residual+LayerNorm ----------------
template <int K>
__global__ __launch_bounds__(256) void mgemm_ln(const short* __restrict__ Ab,
                                                const short* __restrict__ Bw,
                                                const float* __restrict__ bias,
                                                float* __restrict__ hx,
                                                short* __restrict__ hb,
                                                const float* __restrict__ lng,
                                                const float* __restrict__ lnb) {
  __shared__ uint32_t Xs[128 * 32];
  __shared__ uint32_t Wls[128 * 32];
  const int t = threadIdx.x;
  const int wave = t >> 6, lane = t & 63;
  const int g = lane >> 4, p = lane & 15;
  const int wr = wave >> 1, wc = wave & 1;
  const int m0 = blockIdx.x * 128;

  f32x4 acc[4][4];
  #pragma unroll
  for (int i = 0; i < 4; ++i)
    #pragma unroll
    for (int j = 0; j < 4; ++j) acc[i][j] = (f32x4){0.f, 0.f, 0.f, 0.f};

  for (int kt = 0; kt < K; kt += 64) {
    __syncthreads();
    #pragma unroll
    for (int i = 0; i < 4; ++i) {
      const int idx = t + i * 256;
      const int row = idx >> 3, kc = idx & 7;
      const uint4 w = *(const uint4*)(Ab + (size_t)(m0 + row) * K + kt + kc * 8);
      *(uint4*)(Xs + row * 32 + ((kc ^ (row & 7)) << 2)) = w;
      const uint4 u = *(const uint4*)(Bw + (size_t)row * K + kt + kc * 8);
      *(uint4*)(Wls + row * 32 + ((kc ^ (row & 7)) << 2)) = u;
    }
    __syncthreads();
    #pragma unroll
    for (int kc32 = 0; kc32 < 2; ++kc32) {
      bf16x8 xf[4], wf[4];
      #pragma unroll
      for (int mi = 0; mi < 4; ++mi) {
        const int row = wr * 64 + mi * 16 + p;
        union { bf16x8 v; uint4 w; } u;
        u.w = *(const uint4*)(Xs + row * 32 + (((kc32 * 4 + g) ^ (row & 7)) << 2));
        xf[mi] = u.v;
      }
      #pragma unroll
      for (int ni = 0; ni < 4; ++ni) {
        const int row = wc * 64 + ni * 16 + p;
        union { bf16x8 v; uint4 w; } u;
        u.w = *(const uint4*)(Wls + row * 32 + (((kc32 * 4 + g) ^ (row & 7)) << 2));
        wf[ni] = u.v;
      }
      #pragma unroll
      for (int mi = 0; mi < 4; ++mi)
        #pragma unroll
        for (int ni = 0; ni < 4; ++ni)
          acc[mi][ni] = __builtin_amdgcn_mfma_f32_16x16x32_bf16(wf[ni], xf[mi], acc[mi][ni], 0, 0, 0);
    }
  }
  __syncthreads();

  float s1[4] = {0.f, 0.f, 0.f, 0.f};
  float s2[4] = {0.f, 0.f, 0.f, 0.f};
  #pragma unroll
  for (int mi = 0; mi < 4; ++mi) {
    const int m = m0 + wr * 64 + mi * 16 + p;
    #pragma unroll
    for (int ni = 0; ni < 4; ++ni) {
      const int nb = wc * 64 + ni * 16 + g * 4;
      const float4 rv = *(const float4*)(hx + (size_t)m * DD + nb);
      const float4 bv = *(const float4*)(bias + nb);
      acc[mi][ni][0] += bv.x + rv.x;
      acc[mi][ni][1] += bv.y + rv.y;
      acc[mi][ni][2] += bv.z + rv.z;
      acc[mi][ni][3] += bv.w + rv.w;
      #pragma unroll
      for (int r = 0; r < 4; ++r) {
        s1[mi] += acc[mi][ni][r];
        s2[mi] += acc[mi][ni][r] * acc[mi][ni][r];
      }
    }
  }
  float2* red = (float2*)Xs;
  #pragma unroll
  for (int mi = 0; mi < 4; ++mi) {
    const int lr = wr * 64 + mi * 16 + p;
    red[lr * 9 + wc * 4 + g] = make_float2(s1[mi], s2[mi]);
  }
  __syncthreads();
  #pragma unroll
  for (int mi = 0; mi < 4; ++mi) {
    const int lr = wr * 64 + mi * 16 + p;
    float a = 0.f, q = 0.f;
    #pragma unroll
    for (int sslot = 0; sslot < 8; ++sslot) {
      const float2 v = red[lr * 9 + sslot];
      a += v.x; q += v.y;
    }
    const float mu = a * (1.0f / 128.0f);
    const float rs = rsqrtf(fmaxf(q * (1.0f / 128.0f) - mu * mu, 0.0f) + 1e-5f);
    const int m = m0 + lr;
    #pragma unroll
    for (int ni = 0; ni < 4; ++ni) {
      const int nb = wc * 64 + ni * 16 + g * 4;
      const float4 gv = *(const float4*)(lng + nb);
      const float4 bv = *(const float4*)(lnb + nb);
      float c[4];
      c[0] = (acc[mi][ni][0] - mu) * rs * gv.x + bv.x;
      c[1] = (acc[mi][ni][1] - mu) * rs * gv.y + bv.y;
      c[2] = (acc[mi][ni][2] - mu) * rs * gv.z + bv.z;
      c[3] = (acc[mi][ni][3] - mu) * rs * gv.w + bv.w;
      float4 w;
      w.x = c[0]; w.y = c[1]; w.z = c[2]; w.w = c[3];
      *(float4*)(hx + (size_t)m * DD + nb) = w;
      uint2 wb;
      wb.x = pack2(c[0], c[1]);
      wb.y = pack2(c[2], c[3]);
      *(uint2*)(hb + (size_t)m * DD + nb) = wb;
    }
  }
}

// ---------------- Fused FFN: h = LN(h + relu(hb@W1^T + b1)@W2^T + b2) ----------------
// 64-row m-tile per block; ReLU intermediate lives entirely in LDS (no ff1 HBM
// round-trip). 16 nf-chunks of 64: S = hs@W1c^T (K=128), relu+pack -> Ssl,
// acc2 += Ssl@W2c^T (K=64). acc2 (32 AGPR) + S (16 AGPR) — no spill budget.
__global__ __launch_bounds__(256) void ffn_fused_kernel(const short* __restrict__ hbi,
                                                        const short* __restrict__ W1b,
                                                        const float* __restrict__ b1v,
                                                        const short* __restrict__ W2b,
                                                        const float* __restrict__ b2v,
                                                        float* __restrict__ hx,
                                                        short* __restrict__ hbo,
                                                        const float* __restrict__ lng,
                                                        const float* __restrict__ lnb) {
  __shared__ uint32_t HsW[64 * 64];    // 16 KB: hs [64 m][128 k] bf16, 16-slot swizzle
  __shared__ uint32_t W1ls[64 * 64];   // 16 KB: W1 chunk [64 nf][128 k]
  __shared__ uint32_t W2ls[128 * 32];  // 16 KB: W2 chunk [128 n][64 k]
  __shared__ uint32_t Ssl[64 * 32];    // 8 KB: relu(S) [64 m][64 nf] bf16
  const int t = threadIdx.x;
  const int w = t >> 6, lane = t & 63;
  const int g = lane >> 4, p = lane & 15;
  const int m0 = blockIdx.x * 64;

  // stage hs once (coalesced)
  #pragma unroll
  for (int i = 0; i < 4; ++i) {
    const int idx = i * 256 + t;
    const int row = idx >> 4, slot = idx & 15;
    const uint4 u = *(const uint4*)(hbi + (size_t)(m0 + row) * DD + slot * 8);
    *(uint4*)(HsW + row * 64 + ((slot ^ (row & 15)) << 2)) = u;
  }

  f32x4 acc2[4][2];
  #pragma unroll
  for (int i = 0; i < 4; ++i) {
    acc2[i][0] = (f32x4){0.f, 0.f, 0.f, 0.f};
    acc2[i][1] = (f32x4){0.f, 0.f, 0.f, 0.f};
  }

  for (int nf0 = 0; nf0 < FFD; nf0 += 64) {
    __syncthreads();  // prev GEMM2 reads done before overwriting W1ls/W2ls
    #pragma unroll
    for (int i = 0; i < 4; ++i) {
      const int idx = i * 256 + t;
      const int row = idx >> 4, slot = idx & 15;
      const uint4 u = *(const uint4*)(W1b + (size_t)(nf0 + row) * DD + slot * 8);
      *(uint4*)(W1ls + row * 64 + ((slot ^ (row & 15)) << 2)) = u;
    }
    #pragma unroll
    for (int i = 0; i < 4; ++i) {
      const int idx = i * 256 + t;
      const int row = idx >> 3, slot = idx & 7;
      const uint4 u = *(const uint4*)(W2b + (size_t)row * FFD + nf0 + slot * 8);
      *(uint4*)(W2ls + row * 32 + ((slot ^ (row & 7)) << 2)) = u;
    }
    __syncthreads();

    // S = hs @ W1c^T : wave w computes nf-cols [w*16, w*16+16)
    f32x4 S[4];
    #pragma unroll
    for (int i = 0; i < 4; ++i) S[i] = (f32x4){0.f, 0.f, 0.f, 0.f};
    #pragma unroll
    for (int kc = 0; kc < 4; ++kc) {
      bf16x8 af;
      {
        const int row = w * 16 + p;
        union { bf16x8 v; uint4 u; } uu;
        uu.u = *(const uint4*)(W1ls + row * 64 + (((kc * 4 + g) ^ (row & 15)) << 2));
        af = uu.v;
      }
      #pragma unroll
      for (int mi = 0; mi < 4; ++mi) {
        const int row = mi * 16 + p;
        union { bf16x8 v; uint4 u; } uu;
        uu.u = *(const uint4*)(HsW + row * 64 + (((kc * 4 + g) ^ (row & 15)) << 2));
        S[mi] = __builtin_amdgcn_mfma_f32_16x16x32_bf16(af, uu.v, S[mi], 0, 0, 0);
      }
    }
    // bias + relu + pack -> Ssl; thread holds S[m=mi*16+p][nf=w*16+g*4+r]
    const float4 bb = *(const float4*)(b1v + nf0 + w * 16 + g * 4);
    #pragma unroll
    for (int mi = 0; mi < 4; ++mi) {
      const int row = mi * 16 + p;
      const float v0 = fmaxf(S[mi][0] + bb.x, 0.0f);
      const float v1 = fmaxf(S[mi][1] + bb.y, 0.0f);
      const float v2 = fmaxf(S[mi][2] + bb.z, 0.0f);
      const float v3 = fmaxf(S[mi][3] + bb.w, 0.0f);
      const int slot = w * 2 + (g >> 1);
      const int word = row * 32 + ((slot ^ (row & 7)) << 2) + ((g & 1) * 2);
      uint2 pk;
      pk.x = pack2(v0, v1);
      pk.y = pack2(v2, v3);
      *(uint2*)(Ssl + word) = pk;
    }
    __syncthreads();

    // acc2 += Ssl @ W2c^T : wave w owns n-cols [w*32, w*32+32)
    #pragma unroll
    for (int kc = 0; kc < 2; ++kc) {
      bf16x8 xf2[4], wf2[2];
      #pragma unroll
      for (int mi = 0; mi < 4; ++mi) {
        const int row = mi * 16 + p;
        union { bf16x8 v; uint4 u; } uu;
        uu.u = *(const uint4*)(Ssl + row * 32 + (((kc * 4 + g) ^ (row & 7)) << 2));
        xf2[mi] = uu.v;
      }
      #pragma unroll
      for (int ni = 0; ni < 2; ++ni) {
        const int row = w * 32 + ni * 16 + p;
        union { bf16x8 v; uint4 u; } uu;
        uu.u = *(const uint4*)(W2ls + row * 32 + (((kc * 4 + g) ^ (row & 7)) << 2));
        wf2[ni] = uu.v;
      }
      #pragma unroll
      for (int mi = 0; mi < 4; ++mi)
        #pragma unroll
        for (int ni = 0; ni < 2; ++ni)
          acc2[mi][ni] = __builtin_amdgcn_mfma_f32_16x16x32_bf16(wf2[ni], xf2[mi], acc2[mi][ni], 0, 0, 0);
    }
  }
  __syncthreads();

  // epilogue: bias + residual + LN over n=128; writes h fp32 + hb bf16
  float s1[4] = {0.f, 0.f, 0.f, 0.f};
  float s2[4] = {0.f, 0.f, 0.f, 0.f};
  #pragma unroll
  for (int mi = 0; mi < 4; ++mi) {
    const int m = m0 + mi * 16 + p;
    #pragma unroll
    for (int ni = 0; ni < 2; ++ni) {
      const int nb = w * 32 + ni * 16 + g * 4;
      const float4 rv = *(const float4*)(hx + (size_t)m * DD + nb);
      const float4 bv = *(const float4*)(b2v + nb);
      acc2[mi][ni][0] += bv.x + rv.x;
      acc2[mi][ni][1] += bv.y + rv.y;
      acc2[mi][ni][2] += bv.z + rv.z;
      acc2[mi][ni][3] += bv.w + rv.w;
      #pragma unroll
      for (int r = 0; r < 4; ++r) {
        s1[mi] += acc2[mi][ni][r];
        s2[mi] += acc2[mi][ni][r] * acc2[mi][ni][r];
      }
    }
  }
  float2* red = (float2*)W1ls;  // W1ls dead after last chunk
  #pragma unroll
  for (int mi = 0; mi < 4; ++mi) {
    const int lr = mi * 16 + p;
    red[lr * 17 + w * 4 + g] = make_float2(s1[mi], s2[mi]);
  }
  __syncthreads();
  #pragma unroll
  for (int mi = 0; mi < 4; ++mi) {
    const int lr = mi * 16 + p;
    float a = 0.f, q = 0.f;
    #pragma unroll
    for (int sl = 0; sl < 16; ++sl) {
      const float2 v = red[lr * 17 + sl];
      a += v.x; q += v.y;
    }
    const float mu = a * (1.0f / 128.0f);
    const float rs = rsqrtf(fmaxf(q * (1.0f / 128.0f) - mu * mu, 0.0f) + 1e-5f);
    const int m = m0 + lr;
    #pragma unroll
    for (int ni = 0; ni < 2; ++ni) {
      const int nb = w * 32 + ni * 16 + g * 4;
      const float4 gv = *(const float4*)(lng + nb);
      const float4 bv = *(const float4*)(lnb + nb);
      float c[4];
      c[0] = (acc2[mi][ni][0] - mu) * rs * gv.x + bv.x;
      c[1] = (acc2[mi][ni][1] - mu) * rs * gv.y + bv.y;
      c[2] = (acc2[mi][ni][2] - mu) * rs * gv.z + bv.z;
      c[3] = (acc2[mi][ni][3] - mu) * rs * gv.w + bv.w;
      float4 wv;
      wv.x = c[0]; wv.y = c[1]; wv.z = c[2]; wv.w = c[3];
      *(float4*)(hx + (size_t)m * DD + nb) = wv;
      uint2 wb;
      wb.x = pack2(c[0], c[1]);
      wb.y = pack2(c[2], c[3]);
      *(uint2*)(hbo + (size_t)m * DD + nb) = wb;
    }
  }
}

// ---------------- MFMA flash attention v5 ----------------
__global__ __launch_bounds__(512) void attn_mfma_kernel(const short* __restrict__ qkv,
                                                        short* __restrict__ o_out) {
  const int h = blockIdx.x;
  const int b = blockIdx.y;
  const int z = blockIdx.z;
  const int t = threadIdx.x;
  const int wave = t >> 6;
  const int lane = t & 63;
  const int g = lane >> 4;
  const int p = lane & 15;

  __shared__ uint32_t Ks[512 * 8];
  __shared__ uint32_t Vs[16 * 256];

  const short* base = qkv + (size_t)b * SS * 384;

  { // stage K
    const int row = t;
    const short* kp = base + (size_t)row * 384 + DD + h * HDIM;
    const uint4 lo = *(const uint4*)kp;
    const uint4 hi = *(const uint4*)(kp + 8);
    const int f = ((row >> 3) & 1) << 2;
    *(uint4*)(Ks + row * 8 + f) = lo;
    *(uint4*)(Ks + row * 8 + (f ^ 4)) = hi;
  }
  { // stage V^T (swizzled)
    const int k = t;
    const short* vp = base + (size_t)k * 384 + 2 * DD + h * HDIM;
    union { uint4 u[2]; short s[16]; } vv;
    vv.u[0] = *(const uint4*)vp;
    vv.u[1] = *(const uint4*)(vp + 8);
    const int wk = k >> 1;
    #pragma unroll
    for (int d = 0; d < 16; ++d) {
      const int word = d * 256 + (wk ^ ((d & 7) << 2));
      ((short*)(Vs + word))[k & 1] = vv.s[d];
    }
  }
  __syncthreads();

  const bf16x8 zfrag = {0, 0, 0, 0, 0, 0, 0, 0};
  const f32x4 zacc = {0.f, 0.f, 0.f, 0.f};

  #pragma unroll
  for (int qi = 0; qi < 2; ++qi) {
    const int qt = z * 16 + wave + qi * 8;
    bf16x8 qf = zfrag;
    if (g < 2) {
      union { bf16x8 v; uint4 w; } qu;
      qu.w = *(const uint4*)(base + (size_t)(qt * 16 + p) * 384 + h * HDIM + g * 8);
      qf = qu.v;
    }

    f32x4 o = zacc;
    float lsum = 0.0f;

    for (int kv = 0; kv < 16; ++kv) {
      bf16x8 ka = zfrag, kb = zfrag;
      if (g < 2) {
        const int r0 = kv * 32 + 8 * (p >> 2) + (p & 3);
        const int r1 = r0 + 4;
        union { bf16x8 v; uint4 w; } u;
        u.w = *(const uint4*)(Ks + r0 * 8 + ((4 * g) ^ (((r0 >> 3) & 1) << 2)));
        ka = u.v;
        u.w = *(const uint4*)(Ks + r1 * 8 + ((4 * g) ^ (((r1 >> 3) & 1) << 2)));
        kb = u.v;
      }
      union { bf16x8 v; uint4 w; } vu;
      vu.w = *(const uint4*)(Vs + p * 256 + ((kv * 16 + g * 4) ^ ((p & 7) << 2)));

      const f32x4 s0 = __builtin_amdgcn_mfma_f32_16x16x32_bf16(ka, qf, zacc, 0, 0, 0);
      const f32x4 s1 = __builtin_amdgcn_mfma_f32_16x16x32_bf16(kb, qf, zacc, 0, 0, 0);

      float sv0[4], sv1[4];
      #pragma unroll
      for (int r = 0; r < 4; ++r) {
        sv0[r] = __builtin_amdgcn_exp2f(s0[r]);
        sv1[r] = __builtin_amdgcn_exp2f(s1[r]);
      }
      #pragma unroll
      for (int r = 0; r < 4; ++r) lsum += sv0[r] + sv1[r];

      union { bf16x8 v; uint4 w; } pu;
      pu.w.x = pack2(sv0[0], sv0[1]);
      pu.w.y = pack2(sv0[2], sv0[3]);
      pu.w.z = pack2(sv1[0], sv1[1]);
      pu.w.w = pack2(sv1[2], sv1[3]);

      o = __builtin_amdgcn_mfma_f32_16x16x32_bf16(pu.v, vu.v, o, 0, 0, 0);
    }

    lsum += __shfl_xor(lsum, 16);
    lsum += __shfl_xor(lsum, 32);
    const float li = 1.0f / lsum;
    #pragma unroll
    for (int r = 0; r < 4; ++r) {
      const float inv = __shfl(li, 4 * g + r);
      o_out[((size_t)(b * SS + qt * 16 + 4 * g + r)) * DD + h * HDIM + p] =
          (short)(pack2(o[r] * inv, 0.0f) & 0xffff);
    }
  }
}

// ---------------- yn = normalize(sigmoid(h) * x0) rowwise -> bf16 ----------------
__global__ __launch_bounds__(256) void mask_norm_kernel(const float* __restrict__ h,
                                                        const float* __restrict__ x0,
                                                        short* __restrict__ yn) {
  const int wave = threadIdx.x >> 6;
  const int lane = threadIdx.x & 63;
  const size_t row = (size_t)blockIdx.x * 4 + wave;
  const float2 hv = ((const float2*)(h + row * DD))[lane];
  const float2 xv = ((const float2*)(x0 + row * DD))[lane];
  const float a = xv.x / (1.0f + __expf(-hv.x));
  const float c = xv.y / (1.0f + __expf(-hv.y));
  float ss = a * a + c * c;
  #pragma unroll
  for (int off = 1; off < 64; off <<= 1) ss += __shfl_xor(ss, off);
  const float inv = 1.0f / fmaxf(sqrtf(ss), 1e-12f);
  ((uint32_t*)yn)[row * 64 + lane] = pack2(a * inv, c * inv);
}

extern "C" void kernel_launch(void* const* d_in, const int* in_sizes, int n_in,
                              void* d_out, int out_size, void* d_ws, size_t ws_size,
                              hipStream_t stream) {
  const float* src  = (const float*)d_in[0];
  const float* Wqkv = (const float*)d_in[1];
  const float* bqkv = (const float*)d_in[2];
  const float* Wo   = (const float*)d_in[3];
  const float* bo   = (const float*)d_in[4];
  const float* ln1g = (const float*)d_in[5];
  const float* ln1b = (const float*)d_in[6];
  const float* W1   = (const float*)d_in[7];
  const float* b1   = (const float*)d_in[8];
  const float* W2   = (const float*)d_in[9];
  const float* b2   = (const float*)d_in[10];
  const float* ln2g = (const float*)d_in[11];
  const float* ln2b = (const float*)d_in[12];
  float* out = (float*)d_out;

  char* W = (char*)d_ws;
  const size_t MB = 1048576;
  float* x0  = (float*)(W);
  float* h   = (float*)(W + 16 * MB);
  short* hb  = (short*)(W + 32 * MB);
  short* qkv = (short*)(W + 40 * MB);
  short* att = (short*)(W + 128 * MB);
  short* xn  = (short*)(W + 136 * MB);
  short* yn  = (short*)(W + 144 * MB);
  short* wqB = (short*)(W + 152 * MB);
  short* woB = wqB + (size_t)NL * 384 * DD;
  short* w1B = woB + (size_t)NL * DD * DD;
  short* w2B = w1B + (size_t)NL * FFD * DD;
  float* bq2 = (float*)(w2B + (size_t)NL * DD * FFD);

  const dim3 blk(256);
  const int ROWS = BB * SS;

  cvt_qkv_kernel<<<(NL * 384 * 64 + 255) / 256, blk, 0, stream>>>(Wqkv, wqB);
  cvt_kernel<<<(NL * DD * DD / 2 + 255) / 256, blk, 0, stream>>>(Wo, woB, NL * DD * DD / 2);
  cvt_kernel<<<(NL * FFD * DD / 2 + 255) / 256, blk, 0, stream>>>(W1, w1B, NL * FFD * DD / 2);
  cvt_kernel<<<(NL * DD * FFD / 2 + 255) / 256, blk, 0, stream>>>(W2, w2B, NL * DD * FFD / 2);
  scale_bq_kernel<<<(NL * 384 + 255) / 256, blk, 0, stream>>>(bqkv, bq2);

  transpose_kernel<<<4096, blk, 0, stream>>>(src, x0, h, hb);
  rownorm_kernel<<<ROWS / 4, blk, 0, stream>>>(x0, xn);
  mgemm<1, false, false><<<dim3(4, 4, BB), blk, 0, stream>>>(
      xn, xn, nullptr, out, SS, SS, DD, (long)SS * DD, (long)SS * DD, (long)SS * SS);

  for (int l = 0; l < NL; ++l) {
    mgemm<0, true, false><<<dim3(3, ROWS / 128, 1), blk, 0, stream>>>(
        hb, wqB + (size_t)l * 384 * DD, bq2 + l * 384, qkv, ROWS, 384, DD, 0, 0, 0);
    attn_mfma_kernel<<<dim3(HH, BB, 2), dim3(512), 0, stream>>>(qkv, att);
    mgemm_ln<DD><<<dim3(ROWS / 128), blk, 0, stream>>>(
        att, woB + (size_t)l * DD * DD, bo + l * DD, h, hb, ln1g + l * DD, ln1b + l * DD);
    ffn_fused_kernel<<<dim3(ROWS / 64), blk, 0, stream>>>(
        hb, w1B + (size_t)l * FFD * DD, b1 + l * FFD,
        w2B + (size_t)l * DD * FFD, b2 + l * DD, h, hb,
        ln2g + l * DD, ln2b + l * DD);
  }

  mask_norm_kernel<<<ROWS / 4, blk, 0, stream>>>(h, x0, yn);
  mgemm<2, false, false><<<dim3(4, 4, BB), blk, 0, stream>>>(
      yn, yn, nullptr, out, SS, SS, DD, (long)SS * DD, (long)SS * DD, (long)SS * SS);
}

// Round 10
// 641.067 us; speedup vs baseline: 2.3568x; 1.1696x over previous
//
#include <hip/hip_runtime.h>
#include <cstdint>
#include <cstddef>

#define SS 512
#define BB 64
#define DD 128
#define HH 8
#define HDIM 16
#define FFD 1024
#define NL 6

typedef short bf16x8 __attribute__((ext_vector_type(8)));
typedef float f32x4 __attribute__((ext_vector_type(4)));

// hardware packed f32->bf16 (RNE), low16 = a, high16 = b
__device__ inline uint32_t pack2(float a, float b) {
  uint32_t r;
  asm("v_cvt_pk_bf16_f32 %0, %1, %2" : "=v"(r) : "v"(a), "v"(b));
  return r;
}

#define QSCALE 0.36067376022224085f  /* 0.25 * log2(e) */

// ---------------- fp32 -> bf16 convert (weights) ----------------
__global__ __launch_bounds__(256) void cvt_kernel(const float* __restrict__ s,
                                                  short* __restrict__ d, int n2) {
  int i = blockIdx.x * 256 + threadIdx.x;
  if (i < n2) {
    float2 v = ((const float2*)s)[i];
    ((uint32_t*)d)[i] = pack2(v.x, v.y);
  }
}

// qkv weights: scale Q rows (n<128) by 0.25*log2e (score scale folded, log2 domain)
__global__ __launch_bounds__(256) void cvt_qkv_kernel(const float* __restrict__ s,
                                                      short* __restrict__ d) {
  int i = blockIdx.x * 256 + threadIdx.x;
  if (i < NL * 384 * 64) {
    const int within = i % (384 * 64);
    const float sc = (within < 128 * 64) ? QSCALE : 1.0f;
    float2 v = ((const float2*)s)[i];
    ((uint32_t*)d)[i] = pack2(v.x * sc, v.y * sc);
  }
}

__global__ __launch_bounds__(256) void scale_bq_kernel(const float* __restrict__ s,
                                                       float* __restrict__ d) {
  int i = blockIdx.x * 256 + threadIdx.x;
  if (i < NL * 384) {
    const float sc = ((i % 384) < 128) ? QSCALE : 1.0f;
    d[i] = s[i] * sc;
  }
}

// ---------------- transpose (S,B,D) -> (B,S,D): x0 fp32, h fp32, hb bf16 ----------------
__global__ __launch_bounds__(256) void transpose_kernel(const float* __restrict__ src,
                                                        float* __restrict__ x0,
                                                        float* __restrict__ h,
                                                        short* __restrict__ hb) {
  int f = blockIdx.x * 256 + threadIdx.x;
  int b = f >> 14;
  int rem = f & 16383;
  int s = rem >> 5;
  int d4 = rem & 31;
  const float4 v = ((const float4*)src)[((size_t)s * BB + b) * 32 + d4];
  ((float4*)x0)[f] = v;
  ((float4*)h)[f] = v;
  uint2 pb;
  pb.x = pack2(v.x, v.y);
  pb.y = pack2(v.z, v.w);
  ((uint2*)hb)[f] = pb;
}

// ---------------- per-row normalize -> bf16 ----------------
__global__ __launch_bounds__(256) void rownorm_kernel(const float* __restrict__ x,
                                                      short* __restrict__ xn) {
  const int wave = threadIdx.x >> 6;
  const int lane = threadIdx.x & 63;
  const size_t row = (size_t)blockIdx.x * 4 + wave;
  const float2 v = ((const float2*)(x + row * DD))[lane];
  float ss = v.x * v.x + v.y * v.y;
  #pragma unroll
  for (int off = 1; off < 64; off <<= 1) ss += __shfl_xor(ss, off);
  const float r = rsqrtf(ss);
  ((uint32_t*)xn)[row * 64 + lane] = pack2(v.x * r, v.y * r);
}

// ---------------- MFMA GEMM: C[m,n] = epilogue(sum_k A[m,k]*B[n,k]) ----------------
// MODE 0: + bias[n], optional ReLU.  MODE 1: max(.,1e-6).  MODE 2: clip(0.5*(max(.,1e-6)+prev),0.1,0.9)
// QPERM: write head-major qkvp[b][which][h][s][16] (attn reads coalesced).
template <int MODE, bool CBF, bool RELU, bool QPERM>
__global__ __launch_bounds__(256) void mgemm(const short* __restrict__ Ab0,
                                             const short* __restrict__ Bw,
                                             const float* __restrict__ bias,
                                             void* __restrict__ Cp,
                                             int M, int N, int K,
                                             long sA, long sB, long sC) {
  __shared__ uint32_t Xs[128 * 32];
  __shared__ uint32_t Wls[128 * 32];
  const int t = threadIdx.x;
  const int wave = t >> 6, lane = t & 63;
  const int g = lane >> 4, p = lane & 15;
  const int wr = wave >> 1, wc = wave & 1;
  const int m0 = blockIdx.y * 128, n0 = blockIdx.x * 128;
  const int z = blockIdx.z;
  const short* Ab = Ab0 + (size_t)z * sA;
  const short* Bb = Bw + (size_t)z * sB;
  float* Cf = (float*)Cp + (CBF ? (size_t)0 : (size_t)z * sC);
  short* Cb = (short*)Cp;

  f32x4 acc[4][4];
  #pragma unroll
  for (int i = 0; i < 4; ++i)
    #pragma unroll
    for (int j = 0; j < 4; ++j) acc[i][j] = (f32x4){0.f, 0.f, 0.f, 0.f};

  for (int kt = 0; kt < K; kt += 64) {
    __syncthreads();
    #pragma unroll
    for (int i = 0; i < 4; ++i) {
      const int idx = t + i * 256;
      const int row = idx >> 3, kc = idx & 7;
      const uint4 w = *(const uint4*)(Ab + (size_t)(m0 + row) * K + kt + kc * 8);
      *(uint4*)(Xs + row * 32 + ((kc ^ (row & 7)) << 2)) = w;
      const uint4 u = *(const uint4*)(Bb + (size_t)(n0 + row) * K + kt + kc * 8);
      *(uint4*)(Wls + row * 32 + ((kc ^ (row & 7)) << 2)) = u;
    }
    __syncthreads();
    #pragma unroll
    for (int kc32 = 0; kc32 < 2; ++kc32) {
      bf16x8 xf[4], wf[4];
      #pragma unroll
      for (int mi = 0; mi < 4; ++mi) {
        const int row = wr * 64 + mi * 16 + p;
        union { bf16x8 v; uint4 w; } u;
        u.w = *(const uint4*)(Xs + row * 32 + (((kc32 * 4 + g) ^ (row & 7)) << 2));
        xf[mi] = u.v;
      }
      #pragma unroll
      for (int ni = 0; ni < 4; ++ni) {
        const int row = wc * 64 + ni * 16 + p;
        union { bf16x8 v; uint4 w; } u;
        u.w = *(const uint4*)(Wls + row * 32 + (((kc32 * 4 + g) ^ (row & 7)) << 2));
        wf[ni] = u.v;
      }
      #pragma unroll
      for (int mi = 0; mi < 4; ++mi)
        #pragma unroll
        for (int ni = 0; ni < 4; ++ni)
          acc[mi][ni] = __builtin_amdgcn_mfma_f32_16x16x32_bf16(wf[ni], xf[mi], acc[mi][ni], 0, 0, 0);
    }
  }

  #pragma unroll
  for (int mi = 0; mi < 4; ++mi) {
    const int m = m0 + wr * 64 + mi * 16 + p;
    #pragma unroll
    for (int ni = 0; ni < 4; ++ni) {
      const int nb = n0 + wc * 64 + ni * 16 + g * 4;
      float c[4];
      if (MODE == 0) {
        const float4 bv = *(const float4*)(bias + nb);
        const float bp[4] = {bv.x, bv.y, bv.z, bv.w};
        #pragma unroll
        for (int r = 0; r < 4; ++r) {
          c[r] = acc[mi][ni][r] + bp[r];
          if (RELU) c[r] = fmaxf(c[r], 0.0f);
        }
      } else if (MODE == 1) {
        #pragma unroll
        for (int r = 0; r < 4; ++r) c[r] = fmaxf(acc[mi][ni][r], 1e-6f);
      } else {
        const float4 pv = *(const float4*)(Cf + (size_t)m * N + nb);
        const float pp[4] = {pv.x, pv.y, pv.z, pv.w};
        #pragma unroll
        for (int r = 0; r < 4; ++r) {
          float v = fmaxf(acc[mi][ni][r], 1e-6f);
          c[r] = fminf(fmaxf(0.5f * (v + pp[r]), 0.1f), 0.9f);
        }
      }
      if (QPERM) {
        const int bb2 = m >> 9, s = m & 511;
        const int which = nb >> 7, hh = (nb >> 4) & 7, d = nb & 15;
        uint2 w;
        w.x = pack2(c[0], c[1]);
        w.y = pack2(c[2], c[3]);
        *(uint2*)(Cb + ((((size_t)(bb2 * 3 + which) * 8 + hh) * 512 + s) * 16 + d)) = w;
      } else if (CBF) {
        uint2 w;
        w.x = pack2(c[0], c[1]);
        w.y = pack2(c[2], c[3]);
        *(uint2*)(Cb + (size_t)m * N + nb) = w;
      } else {
        float4 w;
        w.x = c[0]; w.y = c[1]; w.z = c[2]; w.w = c[3];
        *(float4*)(Cf + (size_t)m * N + nb) = w;
      }
    }
  }
}

// ---------------- MFMA GEMM (N=128) with fused residual+LayerNorm ----------------
template <int K>
__global__ __launch_bounds__(256) void mgemm_ln(const short* __restrict__ Ab,
                                                const short* __restrict__ Bw,
                                                const float* __restrict__ bias,
                                                float* __restrict__ hx,
                                                short* __restrict__ hb,
                                                const float* __restrict__ lng,
                                                const float* __restrict__ lnb) {
  __shared__ uint32_t Xs[128 * 32];
  __shared__ uint32_t Wls[128 * 32];
  const int t = threadIdx.x;
  const int wave = t >> 6, lane = t & 63;
  const int g = lane >> 4, p = lane & 15;
  const int wr = wave >> 1, wc = wave & 1;
  const int m0 = blockIdx.x * 128;

  f32x4 acc[4][4];
  #pragma unroll
  for (int i = 0; i < 4; ++i)
    #pragma unroll
    for (int j = 0; j < 4; ++j) acc[i][j] = (f32x4){0.f, 0.f, 0.f, 0.f};

  for (int kt = 0; kt < K; kt += 64) {
    __syncthreads();
    #pragma unroll
    for (int i = 0; i < 4; ++i) {
      const int idx = t + i * 256;
      const int row = idx >> 3, kc = idx & 7;
      const uint4 w = *(const uint4*)(Ab + (size_t)(m0 + row) * K + kt + kc * 8);
      *(uint4*)(Xs + row * 32 + ((kc ^ (row & 7)) << 2)) = w;
      const uint4 u = *(const uint4*)(Bw + (size_t)row * K + kt + kc * 8);
      *(uint4*)(Wls + row * 32 + ((kc ^ (row & 7)) << 2)) = u;
    }
    __syncthreads();
    #pragma unroll
    for (int kc32 = 0; kc32 < 2; ++kc32) {
      bf16x8 xf[4], wf[4];
      #pragma unroll
      for (int mi = 0; mi < 4; ++mi) {
        const int row = wr * 64 + mi * 16 + p;
        union { bf16x8 v; uint4 w; } u;
        u.w = *(const uint4*)(Xs + row * 32 + (((kc32 * 4 + g) ^ (row & 7)) << 2));
        xf[mi] = u.v;
      }
      #pragma unroll
      for (int ni = 0; ni < 4; ++ni) {
        const int row = wc * 64 + ni * 16 + p;
        union { bf16x8 v; uint4 w; } u;
        u.w = *(const uint4*)(Wls + row * 32 + (((kc32 * 4 + g) ^ (row & 7)) << 2));
        wf[ni] = u.v;
      }
      #pragma unroll
      for (int mi = 0; mi < 4; ++mi)
        #pragma unroll
        for (int ni = 0; ni < 4; ++ni)
          acc[mi][ni] = __builtin_amdgcn_mfma_f32_16x16x32_bf16(wf[ni], xf[mi], acc[mi][ni], 0, 0, 0);
    }
  }
  __syncthreads();

  float s1[4] = {0.f, 0.f, 0.f, 0.f};
  float s2[4] = {0.f, 0.f, 0.f, 0.f};
  #pragma unroll
  for (int mi = 0; mi < 4; ++mi) {
    const int m = m0 + wr * 64 + mi * 16 + p;
    #pragma unroll
    for (int ni = 0; ni < 4; ++ni) {
      const int nb = wc * 64 + ni * 16 + g * 4;
      const float4 rv = *(const float4*)(hx + (size_t)m * DD + nb);
      const float4 bv = *(const float4*)(bias + nb);
      acc[mi][ni][0] += bv.x + rv.x;
      acc[mi][ni][1] += bv.y + rv.y;
      acc[mi][ni][2] += bv.z + rv.z;
      acc[mi][ni][3] += bv.w + rv.w;
      #pragma unroll
      for (int r = 0; r < 4; ++r) {
        s1[mi] += acc[mi][ni][r];
        s2[mi] += acc[mi][ni][r] * acc[mi][ni][r];
      }
    }
  }
  float2* red = (float2*)Xs;
  #pragma unroll
  for (int mi = 0; mi < 4; ++mi) {
    const int lr = wr * 64 + mi * 16 + p;
    red[lr * 9 + wc * 4 + g] = make_float2(s1[mi], s2[mi]);
  }
  __syncthreads();
  #pragma unroll
  for (int mi = 0; mi < 4; ++mi) {
    const int lr = wr * 64 + mi * 16 + p;
    float a = 0.f, q = 0.f;
    #pragma unroll
    for (int sslot = 0; sslot < 8; ++sslot) {
      const float2 v = red[lr * 9 + sslot];
      a += v.x; q += v.y;
    }
    const float mu = a * (1.0f / 128.0f);
    const float rs = rsqrtf(fmaxf(q * (1.0f / 128.0f) - mu * mu, 0.0f) + 1e-5f);
    const int m = m0 + lr;
    #pragma unroll
    for (int ni = 0; ni < 4; ++ni) {
      const int nb = wc * 64 + ni * 16 + g * 4;
      const float4 gv = *(const float4*)(lng + nb);
      const float4 bv = *(const float4*)(lnb + nb);
      float c[4];
      c[0] = (acc[mi][ni][0] - mu) * rs * gv.x + bv.x;
      c[1] = (acc[mi][ni][1] - mu) * rs * gv.y + bv.y;
      c[2] = (acc[mi][ni][2] - mu) * rs * gv.z + bv.z;
      c[3] = (acc[mi][ni][3] - mu) * rs * gv.w + bv.w;
      float4 w;
      w.x = c[0]; w.y = c[1]; w.z = c[2]; w.w = c[3];
      *(float4*)(hx + (size_t)m * DD + nb) = w;
      uint2 wb;
      wb.x = pack2(c[0], c[1]);
      wb.y = pack2(c[2], c[3]);
      *(uint2*)(hb + (size_t)m * DD + nb) = wb;
    }
  }
}

// ---------------- Fused FFN: h = LN(h + relu(hb@W1^T + b1)@W2^T + b2) ----------------
__global__ __launch_bounds__(256) void ffn_fused_kernel(const short* __restrict__ hbi,
                                                        const short* __restrict__ W1b,
                                                        const float* __restrict__ b1v,
                                                        const short* __restrict__ W2b,
                                                        const float* __restrict__ b2v,
                                                        float* __restrict__ hx,
                                                        short* __restrict__ hbo,
                                                        const float* __restrict__ lng,
                                                        const float* __restrict__ lnb) {
  __shared__ uint32_t HsW[64 * 64];
  __shared__ uint32_t W1ls[64 * 64];
  __shared__ uint32_t W2ls[128 * 32];
  __shared__ uint32_t Ssl[64 * 32];
  const int t = threadIdx.x;
  const int w = t >> 6, lane = t & 63;
  const int g = lane >> 4, p = lane & 15;
  const int m0 = blockIdx.x * 64;

  #pragma unroll
  for (int i = 0; i < 4; ++i) {
    const int idx = i * 256 + t;
    const int row = idx >> 4, slot = idx & 15;
    const uint4 u = *(const uint4*)(hbi + (size_t)(m0 + row) * DD + slot * 8);
    *(uint4*)(HsW + row * 64 + ((slot ^ (row & 15)) << 2)) = u;
  }

  f32x4 acc2[4][2];
  #pragma unroll
  for (int i = 0; i < 4; ++i) {
    acc2[i][0] = (f32x4){0.f, 0.f, 0.f, 0.f};
    acc2[i][1] = (f32x4){0.f, 0.f, 0.f, 0.f};
  }

  for (int nf0 = 0; nf0 < FFD; nf0 += 64) {
    __syncthreads();
    #pragma unroll
    for (int i = 0; i < 4; ++i) {
      const int idx = i * 256 + t;
      const int row = idx >> 4, slot = idx & 15;
      const uint4 u = *(const uint4*)(W1b + (size_t)(nf0 + row) * DD + slot * 8);
      *(uint4*)(W1ls + row * 64 + ((slot ^ (row & 15)) << 2)) = u;
    }
    #pragma unroll
    for (int i = 0; i < 4; ++i) {
      const int idx = i * 256 + t;
      const int row = idx >> 3, slot = idx & 7;
      const uint4 u = *(const uint4*)(W2b + (size_t)row * FFD + nf0 + slot * 8);
      *(uint4*)(W2ls + row * 32 + ((slot ^ (row & 7)) << 2)) = u;
    }
    __syncthreads();

    f32x4 S[4];
    #pragma unroll
    for (int i = 0; i < 4; ++i) S[i] = (f32x4){0.f, 0.f, 0.f, 0.f};
    #pragma unroll
    for (int kc = 0; kc < 4; ++kc) {
      bf16x8 af;
      {
        const int row = w * 16 + p;
        union { bf16x8 v; uint4 u; } uu;
        uu.u = *(const uint4*)(W1ls + row * 64 + (((kc * 4 + g) ^ (row & 15)) << 2));
        af = uu.v;
      }
      #pragma unroll
      for (int mi = 0; mi < 4; ++mi) {
        const int row = mi * 16 + p;
        union { bf16x8 v; uint4 u; } uu;
        uu.u = *(const uint4*)(HsW + row * 64 + (((kc * 4 + g) ^ (row & 15)) << 2));
        S[mi] = __builtin_amdgcn_mfma_f32_16x16x32_bf16(af, uu.v, S[mi], 0, 0, 0);
      }
    }
    const float4 bb = *(const float4*)(b1v + nf0 + w * 16 + g * 4);
    #pragma unroll
    for (int mi = 0; mi < 4; ++mi) {
      const int row = mi * 16 + p;
      const float v0 = fmaxf(S[mi][0] + bb.x, 0.0f);
      const float v1 = fmaxf(S[mi][1] + bb.y, 0.0f);
      const float v2 = fmaxf(S[mi][2] + bb.z, 0.0f);
      const float v3 = fmaxf(S[mi][3] + bb.w, 0.0f);
      const int slot = w * 2 + (g >> 1);
      const int word = row * 32 + ((slot ^ (row & 7)) << 2) + ((g & 1) * 2);
      uint2 pk;
      pk.x = pack2(v0, v1);
      pk.y = pack2(v2, v3);
      *(uint2*)(Ssl + word) = pk;
    }
    __syncthreads();

    #pragma unroll
    for (int kc = 0; kc < 2; ++kc) {
      bf16x8 xf2[4], wf2[2];
      #pragma unroll
      for (int mi = 0; mi < 4; ++mi) {
        const int row = mi * 16 + p;
        union { bf16x8 v; uint4 u; } uu;
        uu.u = *(const uint4*)(Ssl + row * 32 + (((kc * 4 + g) ^ (row & 7)) << 2));
        xf2[mi] = uu.v;
      }
      #pragma unroll
      for (int ni = 0; ni < 2; ++ni) {
        const int row = w * 32 + ni * 16 + p;
        union { bf16x8 v; uint4 u; } uu;
        uu.u = *(const uint4*)(W2ls + row * 32 + (((kc * 4 + g) ^ (row & 7)) << 2));
        wf2[ni] = uu.v;
      }
      #pragma unroll
      for (int mi = 0; mi < 4; ++mi)
        #pragma unroll
        for (int ni = 0; ni < 2; ++ni)
          acc2[mi][ni] = __builtin_amdgcn_mfma_f32_16x16x32_bf16(wf2[ni], xf2[mi], acc2[mi][ni], 0, 0, 0);
    }
  }
  __syncthreads();

  float s1[4] = {0.f, 0.f, 0.f, 0.f};
  float s2[4] = {0.f, 0.f, 0.f, 0.f};
  #pragma unroll
  for (int mi = 0; mi < 4; ++mi) {
    const int m = m0 + mi * 16 + p;
    #pragma unroll
    for (int ni = 0; ni < 2; ++ni) {
      const int nb = w * 32 + ni * 16 + g * 4;
      const float4 rv = *(const float4*)(hx + (size_t)m * DD + nb);
      const float4 bv = *(const float4*)(b2v + nb);
      acc2[mi][ni][0] += bv.x + rv.x;
      acc2[mi][ni][1] += bv.y + rv.y;
      acc2[mi][ni][2] += bv.z + rv.z;
      acc2[mi][ni][3] += bv.w + rv.w;
      #pragma unroll
      for (int r = 0; r < 4; ++r) {
        s1[mi] += acc2[mi][ni][r];
        s2[mi] += acc2[mi][ni][r] * acc2[mi][ni][r];
      }
    }
  }
  float2* red = (float2*)W1ls;
  #pragma unroll
  for (int mi = 0; mi < 4; ++mi) {
    const int lr = mi * 16 + p;
    red[lr * 17 + w * 4 + g] = make_float2(s1[mi], s2[mi]);
  }
  __syncthreads();
  #pragma unroll
  for (int mi = 0; mi < 4; ++mi) {
    const int lr = mi * 16 + p;
    float a = 0.f, q = 0.f;
    #pragma unroll
    for (int sl = 0; sl < 16; ++sl) {
      const float2 v = red[lr * 17 + sl];
      a += v.x; q += v.y;
    }
    const float mu = a * (1.0f / 128.0f);
    const float rs = rsqrtf(fmaxf(q * (1.0f / 128.0f) - mu * mu, 0.0f) + 1e-5f);
    const int m = m0 + lr;
    #pragma unroll
    for (int ni = 0; ni < 2; ++ni) {
      const int nb = w * 32 + ni * 16 + g * 4;
      const float4 gv = *(const float4*)(lng + nb);
      const float4 bv = *(const float4*)(lnb + nb);
      float c[4];
      c[0] = (acc2[mi][ni][0] - mu) * rs * gv.x + bv.x;
      c[1] = (acc2[mi][ni][1] - mu) * rs * gv.y + bv.y;
      c[2] = (acc2[mi][ni][2] - mu) * rs * gv.z + bv.z;
      c[3] = (acc2[mi][ni][3] - mu) * rs * gv.w + bv.w;
      float4 wv;
      wv.x = c[0]; wv.y = c[1]; wv.z = c[2]; wv.w = c[3];
      *(float4*)(hx + (size_t)m * DD + nb) = wv;
      uint2 wb;
      wb.x = pack2(c[0], c[1]);
      wb.y = pack2(c[2], c[3]);
      *(uint2*)(hbo + (size_t)m * DD + nb) = wb;
    }
  }
}

// ---------------- MFMA flash attention v6: head-major qkvp, coalesced staging ----------------
__global__ __launch_bounds__(512) void attn_mfma_kernel(const short* __restrict__ qkvp,
                                                        short* __restrict__ o_out) {
  const int h = blockIdx.x;
  const int b = blockIdx.y;
  const int z = blockIdx.z;
  const int t = threadIdx.x;
  const int wave = t >> 6;
  const int lane = t & 63;
  const int g = lane >> 4;
  const int p = lane & 15;

  __shared__ uint32_t Ks[512 * 8];
  __shared__ uint32_t Vs[16 * 256];

  const short* baseQ = qkvp + ((size_t)(b * 3 + 0) * 8 + h) * 8192;
  const short* baseK = qkvp + ((size_t)(b * 3 + 1) * 8 + h) * 8192;
  const short* baseV = qkvp + ((size_t)(b * 3 + 2) * 8 + h) * 8192;

  { // stage K: row t, contiguous 32B/lane
    const int row = t;
    const uint4 lo = *(const uint4*)(baseK + row * 16);
    const uint4 hi = *(const uint4*)(baseK + row * 16 + 8);
    const int f = ((row >> 3) & 1) << 2;
    *(uint4*)(Ks + row * 8 + f) = lo;
    *(uint4*)(Ks + row * 8 + (f ^ 4)) = hi;
  }
  { // stage V^T (swizzled scatter), contiguous read
    const int k = t;
    union { uint4 u[2]; short s[16]; } vv;
    vv.u[0] = *(const uint4*)(baseV + k * 16);
    vv.u[1] = *(const uint4*)(baseV + k * 16 + 8);
    const int wk = k >> 1;
    #pragma unroll
    for (int d = 0; d < 16; ++d) {
      const int word = d * 256 + (wk ^ ((d & 7) << 2));
      ((short*)(Vs + word))[k & 1] = vv.s[d];
    }
  }
  __syncthreads();

  const bf16x8 zfrag = {0, 0, 0, 0, 0, 0, 0, 0};
  const f32x4 zacc = {0.f, 0.f, 0.f, 0.f};

  #pragma unroll
  for (int qi = 0; qi < 2; ++qi) {
    const int qt = z * 16 + wave + qi * 8;
    bf16x8 qf = zfrag;
    if (g < 2) {
      union { bf16x8 v; uint4 w; } qu;
      qu.w = *(const uint4*)(baseQ + (qt * 16 + p) * 16 + g * 8);
      qf = qu.v;
    }

    f32x4 o = zacc;
    float lsum = 0.0f;

    for (int kv = 0; kv < 16; ++kv) {
      bf16x8 ka = zfrag, kb = zfrag;
      if (g < 2) {
        const int r0 = kv * 32 + 8 * (p >> 2) + (p & 3);
        const int r1 = r0 + 4;
        union { bf16x8 v; uint4 w; } u;
        u.w = *(const uint4*)(Ks + r0 * 8 + ((4 * g) ^ (((r0 >> 3) & 1) << 2)));
        ka = u.v;
        u.w = *(const uint4*)(Ks + r1 * 8 + ((4 * g) ^ (((r1 >> 3) & 1) << 2)));
        kb = u.v;
      }
      union { bf16x8 v; uint4 w; } vu;
      vu.w = *(const uint4*)(Vs + p * 256 + ((kv * 16 + g * 4) ^ ((p & 7) << 2)));

      const f32x4 s0 = __builtin_amdgcn_mfma_f32_16x16x32_bf16(ka, qf, zacc, 0, 0, 0);
      const f32x4 s1 = __builtin_amdgcn_mfma_f32_16x16x32_bf16(kb, qf, zacc, 0, 0, 0);

      float sv0[4], sv1[4];
      #pragma unroll
      for (int r = 0; r < 4; ++r) {
        sv0[r] = __builtin_amdgcn_exp2f(s0[r]);
        sv1[r] = __builtin_amdgcn_exp2f(s1[r]);
      }
      #pragma unroll
      for (int r = 0; r < 4; ++r) lsum += sv0[r] + sv1[r];

      union { bf16x8 v; uint4 w; } pu;
      pu.w.x = pack2(sv0[0], sv0[1]);
      pu.w.y = pack2(sv0[2], sv0[3]);
      pu.w.z = pack2(sv1[0], sv1[1]);
      pu.w.w = pack2(sv1[2], sv1[3]);

      o = __builtin_amdgcn_mfma_f32_16x16x32_bf16(pu.v, vu.v, o, 0, 0, 0);
    }

    lsum += __shfl_xor(lsum, 16);
    lsum += __shfl_xor(lsum, 32);
    const float li = 1.0f / lsum;
    #pragma unroll
    for (int r = 0; r < 4; ++r) {
      const float inv = __shfl(li, 4 * g + r);
      o_out[((size_t)(b * SS + qt * 16 + 4 * g + r)) * DD + h * HDIM + p] =
          (short)(pack2(o[r] * inv, 0.0f) & 0xffff);
    }
  }
}

// ---------------- yn = normalize(sigmoid(h) * x0) rowwise -> bf16 ----------------
__global__ __launch_bounds__(256) void mask_norm_kernel(const float* __restrict__ h,
                                                        const float* __restrict__ x0,
                                                        short* __restrict__ yn) {
  const int wave = threadIdx.x >> 6;
  const int lane = threadIdx.x & 63;
  const size_t row = (size_t)blockIdx.x * 4 + wave;
  const float2 hv = ((const float2*)(h + row * DD))[lane];
  const float2 xv = ((const float2*)(x0 + row * DD))[lane];
  const float a = xv.x / (1.0f + __expf(-hv.x));
  const float c = xv.y / (1.0f + __expf(-hv.y));
  float ss = a * a + c * c;
  #pragma unroll
  for (int off = 1; off < 64; off <<= 1) ss += __shfl_xor(ss, off);
  const float inv = 1.0f / fmaxf(sqrtf(ss), 1e-12f);
  ((uint32_t*)yn)[row * 64 + lane] = pack2(a * inv, c * inv);
}

extern "C" void kernel_launch(void* const* d_in, const int* in_sizes, int n_in,
                              void* d_out, int out_size, void* d_ws, size_t ws_size,
                              hipStream_t stream) {
  const float* src  = (const float*)d_in[0];
  const float* Wqkv = (const float*)d_in[1];
  const float* bqkv = (const float*)d_in[2];
  const float* Wo   = (const float*)d_in[3];
  const float* bo   = (const float*)d_in[4];
  const float* ln1g = (const float*)d_in[5];
  const float* ln1b = (const float*)d_in[6];
  const float* W1   = (const float*)d_in[7];
  const float* b1   = (const float*)d_in[8];
  const float* W2   = (const float*)d_in[9];
  const float* b2   = (const float*)d_in[10];
  const float* ln2g = (const float*)d_in[11];
  const float* ln2b = (const float*)d_in[12];
  float* out = (float*)d_out;

  char* W = (char*)d_ws;
  const size_t MB = 1048576;
  float* x0  = (float*)(W);
  float* h   = (float*)(W + 16 * MB);
  short* hb  = (short*)(W + 32 * MB);
  short* qkvp = (short*)(W + 40 * MB);   // 24 MB head-major [b][3][h][s][16]
  short* att = (short*)(W + 128 * MB);
  short* xn  = (short*)(W + 136 * MB);
  short* yn  = (short*)(W + 144 * MB);
  short* wqB = (short*)(W + 152 * MB);
  short* woB = wqB + (size_t)NL * 384 * DD;
  short* w1B = woB + (size_t)NL * DD * DD;
  short* w2B = w1B + (size_t)NL * FFD * DD;
  float* bq2 = (float*)(w2B + (size_t)NL * DD * FFD);

  const dim3 blk(256);
  const int ROWS = BB * SS;

  cvt_qkv_kernel<<<(NL * 384 * 64 + 255) / 256, blk, 0, stream>>>(Wqkv, wqB);
  cvt_kernel<<<(NL * DD * DD / 2 + 255) / 256, blk, 0, stream>>>(Wo, woB, NL * DD * DD / 2);
  cvt_kernel<<<(NL * FFD * DD / 2 + 255) / 256, blk, 0, stream>>>(W1, w1B, NL * FFD * DD / 2);
  cvt_kernel<<<(NL * DD * FFD / 2 + 255) / 256, blk, 0, stream>>>(W2, w2B, NL * DD * FFD / 2);
  scale_bq_kernel<<<(NL * 384 + 255) / 256, blk, 0, stream>>>(bqkv, bq2);

  transpose_kernel<<<4096, blk, 0, stream>>>(src, x0, h, hb);
  rownorm_kernel<<<ROWS / 4, blk, 0, stream>>>(x0, xn);
  mgemm<1, false, false, false><<<dim3(4, 4, BB), blk, 0, stream>>>(
      xn, xn, nullptr, out, SS, SS, DD, (long)SS * DD, (long)SS * DD, (long)SS * SS);

  for (int l = 0; l < NL; ++l) {
    mgemm<0, true, false, true><<<dim3(3, ROWS / 128, 1), blk, 0, stream>>>(
        hb, wqB + (size_t)l * 384 * DD, bq2 + l * 384, qkvp, ROWS, 384, DD, 0, 0, 0);
    attn_mfma_kernel<<<dim3(HH, BB, 2), dim3(512), 0, stream>>>(qkvp, att);
    mgemm_ln<DD><<<dim3(ROWS / 128), blk, 0, stream>>>(
        att, woB + (size_t)l * DD * DD, bo + l * DD, h, hb, ln1g + l * DD, ln1b + l * DD);
    ffn_fused_kernel<<<dim3(ROWS / 64), blk, 0, stream>>>(
        hb, w1B + (size_t)l * FFD * DD, b1 + l * FFD,
        w2B + (size_t)l * DD * FFD, b2 + l * DD, h, hb,
        ln2g + l * DD, ln2b + l * DD);
  }

  mask_norm_kernel<<<ROWS / 4, blk, 0, stream>>>(h, x0, yn);
  mgemm<2, false, false, false><<<dim3(4, 4, BB), blk, 0, stream>>>(
      yn, yn, nullptr, out, SS, SS, DD, (long)SS * DD, (long)SS * DD, (long)SS * SS);
}